// Round 4
// baseline (38589.908 us; speedup 1.0000x reference)
//
#include <hip/hip_runtime.h>
#include <hip/hip_cooperative_groups.h>
#include <cstdint>
#include <cstddef>

namespace cg = cooperative_groups;

#define BB   64
#define SEQL 512
#define INF  512
#define HID  1024
#define GG   4096   // 4*HID

#define MU_    0.9f
#define SSTEP_ 0.1f
#define BETA_  0.999f
#define EPS_   1e-16f
#define SCL    2048.0f
#define ISCL   (1.0f / 2048.0f)

typedef _Float16 half8 __attribute__((ext_vector_type(8)));
typedef float f32x4 __attribute__((ext_vector_type(4)));

// D = A*B + C, 16x16x32 f16. Builtin => compiler handles all hazards/waits.
__device__ __forceinline__ f32x4 mfma16(half8 a, half8 b, f32x4 c) {
  return __builtin_amdgcn_mfma_f32_16x16x32_f16(a, b, c, 0, 0, 0);
}

// f32 -> (hi, lo*2048) f16 split: x ~= hi + lo/2048, rel residual ~2^-22.
__device__ __forceinline__ void fsplit(float v, _Float16& hi, _Float16& lo) {
  hi = (_Float16)v;
  lo = (_Float16)((v - (float)hi) * SCL);
}

// ---- transpose + f16-split: src [R][C] f32 -> dhi/dlo [C][R] f16 ----
__global__ __launch_bounds__(256) void transpose_split(const float* __restrict__ src,
                                                       _Float16* __restrict__ dhi,
                                                       _Float16* __restrict__ dlo,
                                                       int R, int C) {
  __shared__ float tile[32][33];
  int c0 = blockIdx.x * 32, r0 = blockIdx.y * 32;
  int tx = threadIdx.x & 31, ty = threadIdx.x >> 5;  // 32 x 8
#pragma unroll
  for (int i = 0; i < 32; i += 8)
    tile[ty + i][tx] = src[(size_t)(r0 + ty + i) * C + (c0 + tx)];
  __syncthreads();
#pragma unroll
  for (int i = 0; i < 32; i += 8) {
    float v = tile[tx][ty + i];
    _Float16 hi, lo;
    fsplit(v, hi, lo);
    size_t o = (size_t)(c0 + ty + i) * R + (r0 + tx);
    dhi[o] = hi;
    dlo[o] = lo;
  }
}

// ---- h0 -> f16 split planes ----
__global__ __launch_bounds__(256) void init_h(const float* __restrict__ h0,
                                              _Float16* __restrict__ hhi,
                                              _Float16* __restrict__ hlo) {
  int i = blockIdx.x * 256 + threadIdx.x;
  _Float16 hi, lo;
  fsplit(h0[i], hi, lo);
  hhi[i] = hi;
  hlo[i] = lo;
}

// ---- persistent recurrent kernel: all 512 steps, 1 grid.sync per step.
// grid 256 wgs x 512 thr. wg = (nb = bid>>2 : 16 cells, rt = bid&3 : 16 rows).
// wave w: gate q = w&3, K-half kh = w>>2. Fused: rec GEMM (K=1024, h-split) +
// grad GEMM (K=512, x split on the fly). v/m/c live in registers across steps.
__global__ __launch_bounds__(512, 1) void rnn_persist(
    const float* __restrict__ x,
    const _Float16* __restrict__ wih_hi, const _Float16* __restrict__ wih_lo,
    const _Float16* __restrict__ whh_hi, const _Float16* __restrict__ whh_lo,
    const float* __restrict__ bih, const float* __restrict__ bhh,
    const float* __restrict__ v0, const float* __restrict__ m0,
    const float* __restrict__ c0,
    _Float16* __restrict__ hA_hi, _Float16* __restrict__ hA_lo,
    _Float16* __restrict__ hB_hi, _Float16* __restrict__ hB_lo,
    float* __restrict__ lout, float* __restrict__ hout,
    float* __restrict__ cout, float* __restrict__ vout,
    float* __restrict__ mout) {
  cg::grid_group grid = cg::this_grid();

  __shared__ float ldsR[8][64][4];  // rec partials per wave
  __shared__ float ldsG[8][64][4];  // grad partials per wave

  int tid = threadIdx.x;
  int wave = tid >> 6, lane = tid & 63;
  int l15 = lane & 15, lg = lane >> 4;
  int q = wave & 3, kh = wave >> 2;
  int nb = blockIdx.x >> 2, rt = blockIdx.x & 3;

  // GEMM operand bases (constant across t)
  int grow = q * HID + nb * 16 + l15;  // weight row (gate column of output)
  int brow = rt * 16 + l15;            // batch row (A-fragment row)
  const _Float16* wrh = whh_hi + (size_t)grow * HID + kh * 512 + lg * 8;
  const _Float16* wrl = whh_lo + (size_t)grow * HID + kh * 512 + lg * 8;
  const _Float16* wgh = wih_hi + (size_t)grow * INF + kh * 256 + lg * 8;
  const _Float16* wgl = wih_lo + (size_t)grow * INF + kh * 256 + lg * 8;
  const float*    xrw = x + (size_t)brow * (SEQL * INF) + kh * 256 + lg * 8;
  size_t hoff = (size_t)brow * HID + kh * 512 + lg * 8;

  // epilogue thread state (threads 0..255): one (batch row, cell) pair
  int erow = tid >> 4, ecol = tid & 15;      // 16x16
  int eb = rt * 16 + erow, en = nb * 16 + ecol;
  int lane2 = (erow >> 2) * 16 + ecol, rr = erow & 3;
  float vreg[4], mreg[4], creg = 0.0f, bi[4], bh2[4];
  if (tid < 256) {
#pragma unroll
    for (int q2 = 0; q2 < 4; q2++) {
      size_t gi = (size_t)eb * GG + q2 * HID + en;
      vreg[q2] = v0[gi];
      mreg[q2] = m0[gi];
      bi[q2] = bih[q2 * HID + en];
      bh2[q2] = bhh[q2 * HID + en];
    }
    creg = c0[(size_t)eb * HID + en];
  }

  for (int t = 0; t < SEQL; ++t) {
    const _Float16* rh = (t & 1) ? hB_hi : hA_hi;
    const _Float16* rl = (t & 1) ? hB_lo : hA_lo;

    f32x4 aRM = {}, aRL = {}, aGM = {}, aGL = {};
    // recurrent GEMM: K-half of 1024
#pragma unroll 4
    for (int kk = 0; kk < 512; kk += 32) {
      half8 ah = *(const half8*)(rh + hoff + kk);
      half8 al = *(const half8*)(rl + hoff + kk);
      half8 bh = *(const half8*)(wrh + kk);
      half8 bl = *(const half8*)(wrl + kk);
      aRM = mfma16(ah, bh, aRM);
      aRL = mfma16(al, bh, aRL);
      aRL = mfma16(ah, bl, aRL);
    }
    // input GEMM: K-half of 512, x split on the fly
    const float* xt = xrw + (size_t)t * INF;
#pragma unroll 2
    for (int kk = 0; kk < 256; kk += 32) {
      f32x4 x0 = *(const f32x4*)(xt + kk);
      f32x4 x1 = *(const f32x4*)(xt + kk + 4);
      half8 ah, al;
#pragma unroll
      for (int j = 0; j < 4; j++) {
        _Float16 hi, lo;
        fsplit(x0[j], hi, lo); ah[j] = hi; al[j] = lo;
        fsplit(x1[j], hi, lo); ah[4 + j] = hi; al[4 + j] = lo;
      }
      half8 bh = *(const half8*)(wgh + kk);
      half8 bl = *(const half8*)(wgl + kk);
      aGM = mfma16(ah, bh, aGM);
      aGL = mfma16(al, bh, aGL);
      aGL = mfma16(ah, bl, aGL);
    }
#pragma unroll
    for (int i = 0; i < 4; i++) {
      ldsR[wave][lane][i] = aRM[i] + aRL[i] * ISCL;
      ldsG[wave][lane][i] = aGM[i] + aGL[i] * ISCL;
    }
    __syncthreads();

    if (tid < 256) {
      float gate[4];
#pragma unroll
      for (int q2 = 0; q2 < 4; q2++) {
        float rec = ldsR[q2][lane2][rr] + ldsR[q2 + 4][lane2][rr];
        float gr  = ldsG[q2][lane2][rr] + ldsG[q2 + 4][lane2][rr] + bi[q2];
        vreg[q2] = MU_ * vreg[q2] + SSTEP_ * gr;
        mreg[q2] = BETA_ * mreg[q2] + (1.0f - BETA_) * gr * gr;
        gate[q2] = vreg[q2] / (sqrtf(mreg[q2]) + EPS_) + rec + bh2[q2];
      }
      float ig = 1.0f / (1.0f + expf(-gate[0]));
      float fg = 1.0f / (1.0f + expf(-gate[1]));
      float gg = tanhf(gate[2]);
      float og = 1.0f / (1.0f + expf(-gate[3]));
      creg = creg * fg + ig * gg;
      float hh = og * tanhf(creg);

      lout[(size_t)eb * (SEQL * HID) + (size_t)t * HID + en] = hh;
      _Float16 shi, slo;
      fsplit(hh, shi, slo);
      size_t hidx = (size_t)eb * HID + en;
      _Float16* wh = (t & 1) ? hA_hi : hB_hi;
      _Float16* wl = (t & 1) ? hA_lo : hB_lo;
      wh[hidx] = shi;
      wl[hidx] = slo;
      if (t == SEQL - 1) {
        hout[hidx] = hh;
        cout[hidx] = creg;
#pragma unroll
        for (int q2 = 0; q2 < 4; q2++) {
          size_t gi = (size_t)eb * GG + q2 * HID + en;
          vout[gi] = vreg[q2];
          mout[gi] = mreg[q2];
        }
      }
      __threadfence();
    }
    grid.sync();
  }
}

extern "C" void kernel_launch(void* const* d_in, const int* in_sizes, int n_in,
                              void* d_out, int out_size, void* d_ws, size_t ws_size,
                              hipStream_t stream) {
  const float* x   = (const float*)d_in[0];
  const float* wih = (const float*)d_in[1];
  const float* whh = (const float*)d_in[2];
  const float* bih = (const float*)d_in[3];
  const float* bhh = (const float*)d_in[4];
  const float* h0  = (const float*)d_in[5];
  const float* c0  = (const float*)d_in[6];
  const float* v0  = (const float*)d_in[7];
  const float* m0  = (const float*)d_in[8];

  float* out  = (float*)d_out;
  float* lout = out;                                  // [B][S][H]
  float* hout = out + (size_t)BB * SEQL * HID;        // [B][H]
  float* cout = hout + (size_t)BB * HID;              // [B][H]
  float* vout = cout + (size_t)BB * HID;              // [B][G]
  float* mout = vout + (size_t)BB * GG;               // [B][G]

  char* ws = (char*)d_ws;
  size_t o = 0;
  _Float16* wih_hi = (_Float16*)(ws + o); o += (size_t)GG * INF * 2;   // 4 MiB
  _Float16* wih_lo = (_Float16*)(ws + o); o += (size_t)GG * INF * 2;   // 4 MiB
  _Float16* whh_hi = (_Float16*)(ws + o); o += (size_t)GG * HID * 2;   // 8 MiB
  _Float16* whh_lo = (_Float16*)(ws + o); o += (size_t)GG * HID * 2;   // 8 MiB
  _Float16* hA_hi  = (_Float16*)(ws + o); o += (size_t)BB * HID * 2;   // 128 KiB
  _Float16* hA_lo  = (_Float16*)(ws + o); o += (size_t)BB * HID * 2;
  _Float16* hB_hi  = (_Float16*)(ws + o); o += (size_t)BB * HID * 2;
  _Float16* hB_lo  = (_Float16*)(ws + o); o += (size_t)BB * HID * 2;

  transpose_split<<<dim3(GG / 32, INF / 32), 256, 0, stream>>>(wih, wih_hi, wih_lo, INF, GG);
  transpose_split<<<dim3(GG / 32, HID / 32), 256, 0, stream>>>(whh, whh_hi, whh_lo, HID, GG);
  init_h<<<(BB * HID) / 256, 256, 0, stream>>>(h0, hA_hi, hA_lo);

  void* args[] = {
    (void*)&x, (void*)&wih_hi, (void*)&wih_lo, (void*)&whh_hi, (void*)&whh_lo,
    (void*)&bih, (void*)&bhh, (void*)&v0, (void*)&m0, (void*)&c0,
    (void*)&hA_hi, (void*)&hA_lo, (void*)&hB_hi, (void*)&hB_lo,
    (void*)&lout, (void*)&hout, (void*)&cout, (void*)&vout, (void*)&mout,
  };
  hipLaunchCooperativeKernel(reinterpret_cast<void*>(rnn_persist),
                             dim3(256), dim3(512), args, 0, stream);
}

// Round 5
// 35970.831 us; speedup vs baseline: 1.0728x; 1.0728x over previous
//
#include <hip/hip_runtime.h>
#include <hip/hip_cooperative_groups.h>
#include <cstdint>
#include <cstddef>

namespace cg = cooperative_groups;

#define BB   64
#define SEQL 512
#define INF  512
#define HID  1024
#define GG   4096   // 4*HID

#define MU_    0.9f
#define SSTEP_ 0.1f
#define BETA_  0.999f
#define EPS_   1e-16f
#define SCL    2048.0f
#define ISCL   (1.0f / 2048.0f)

#define WROW 1544                 // 1536 + 8 pad (halves) -> conflict-free b128
#define WPLN (16 * WROW)          // plane stride (halves)
#define WBYTES (2 * WPLN * 2)     // 98816 B
#define RBYTES (8 * 64 * 4 * 4)   // 8192 B per reduce buffer
#define SMEM_BYTES (WBYTES + 2 * RBYTES)  // 115200 B

typedef _Float16 half8 __attribute__((ext_vector_type(8)));
typedef float f32x4 __attribute__((ext_vector_type(4)));

// D = A*B + C, 16x16x32 f16. Builtin => compiler handles all hazards/waits.
__device__ __forceinline__ f32x4 mfma16(half8 a, half8 b, f32x4 c) {
  return __builtin_amdgcn_mfma_f32_16x16x32_f16(a, b, c, 0, 0, 0);
}

// f32 -> (hi, lo*2048) f16 split: x ~= hi + lo/2048, rel residual ~2^-22.
__device__ __forceinline__ void fsplit(float v, _Float16& hi, _Float16& lo) {
  hi = (_Float16)v;
  lo = (_Float16)((v - (float)hi) * SCL);
}

// ---- transpose + f16-split: src [R][C] f32 -> dhi/dlo [C][R] f16 ----
__global__ __launch_bounds__(256) void transpose_split(const float* __restrict__ src,
                                                       _Float16* __restrict__ dhi,
                                                       _Float16* __restrict__ dlo,
                                                       int R, int C) {
  __shared__ float tile[32][33];
  int c0 = blockIdx.x * 32, r0 = blockIdx.y * 32;
  int tx = threadIdx.x & 31, ty = threadIdx.x >> 5;  // 32 x 8
#pragma unroll
  for (int i = 0; i < 32; i += 8)
    tile[ty + i][tx] = src[(size_t)(r0 + ty + i) * C + (c0 + tx)];
  __syncthreads();
#pragma unroll
  for (int i = 0; i < 32; i += 8) {
    float v = tile[tx][ty + i];
    _Float16 hi, lo;
    fsplit(v, hi, lo);
    size_t o = (size_t)(c0 + ty + i) * R + (r0 + tx);
    dhi[o] = hi;
    dlo[o] = lo;
  }
}

// ---- h0 -> f16 split planes ----
__global__ __launch_bounds__(256) void init_h(const float* __restrict__ h0,
                                              _Float16* __restrict__ hhi,
                                              _Float16* __restrict__ hlo) {
  int i = blockIdx.x * 256 + threadIdx.x;
  _Float16 hi, lo;
  fsplit(h0[i], hi, lo);
  hhi[i] = hi;
  hlo[i] = lo;
}

// ---- persistent recurrent kernel: all 512 steps, 1 grid.sync per step.
// grid 256 wgs x 512 thr. wg nb owns cells nb*4..nb*4+3 (all 4 gates, all 64
// batch rows). Weights (16 G-rows x K=1536, hi+lo) live in LDS for the whole
// run. wave w: batch-tile bt = w&3 (16 rows), K-half kh = w>>2.
// v/m/c live in epilogue-thread registers across all steps.
__global__ __launch_bounds__(512, 1) void rnn_persist(
    const float* __restrict__ x,
    const _Float16* __restrict__ wih_hi, const _Float16* __restrict__ wih_lo,
    const _Float16* __restrict__ whh_hi, const _Float16* __restrict__ whh_lo,
    const float* __restrict__ bih, const float* __restrict__ bhh,
    const float* __restrict__ v0, const float* __restrict__ m0,
    const float* __restrict__ c0,
    _Float16* __restrict__ hA_hi, _Float16* __restrict__ hA_lo,
    _Float16* __restrict__ hB_hi, _Float16* __restrict__ hB_lo,
    float* __restrict__ lout, float* __restrict__ hout,
    float* __restrict__ cout, float* __restrict__ vout,
    float* __restrict__ mout) {
  cg::grid_group grid = cg::this_grid();

  extern __shared__ char smem[];
  _Float16* Wsh = (_Float16*)smem;                 // [2 planes][16 rows][WROW]
  float* ldsR = (float*)(smem + WBYTES);           // [8][64][4]
  float* ldsG = (float*)(smem + WBYTES + RBYTES);  // [8][64][4]

  int tid = threadIdx.x;
  int wave = tid >> 6, lane = tid & 63;
  int l15 = lane & 15, lg = lane >> 4;
  int bt = wave & 3, kh = wave >> 2;
  int nb = blockIdx.x;  // cell block: cells nb*4 .. nb*4+3

  // ---- one-time: stage this wg's weight slice into LDS ----
  // LDS row r = q*4+j  <->  global weight row q*HID + nb*4 + j.
  for (int p = 0; p < 2; ++p) {
    const _Float16* Sh = p ? whh_lo : whh_hi;  // [G][HID]
    const _Float16* Si = p ? wih_lo : wih_hi;  // [G][INF]
    for (int c = tid; c < 16 * 192; c += 512) {
      int r = c / 192, cc = c % 192;  // cc: 16B chunk (8 halves) within row
      int grow = (r >> 2) * HID + nb * 4 + (r & 3);
      half8 v;
      if (cc < 128) v = *(const half8*)(Sh + (size_t)grow * HID + cc * 8);
      else          v = *(const half8*)(Si + (size_t)grow * INF + (cc - 128) * 8);
      *(half8*)(Wsh + p * WPLN + r * WROW + cc * 8) = v;
    }
  }

  // GEMM operand bases (constant across t)
  const _Float16* Wp0 = Wsh;          // hi plane
  const _Float16* Wp1 = Wsh + WPLN;   // lo plane
  int lk_rec  = l15 * WROW + kh * 512 + lg * 8;
  int lk_grad = l15 * WROW + 1024 + kh * 256 + lg * 8;
  size_t hbase = (size_t)(bt * 16 + l15) * HID + kh * 512 + lg * 8;
  const float* xbase = x + (size_t)(bt * 16 + l15) * (SEQL * INF) + kh * 256 + lg * 8;

  // epilogue thread state (threads 0..255): thread = (batch bo, cell j)
  int bo = tid >> 2, j = tid & 3;
  int en = nb * 4 + j;                       // global cell index
  int bt2 = bo >> 4, bi2 = bo & 15;
  int lg2 = bi2 >> 2, rg = bi2 & 3;
  float vreg[4], mreg[4], creg = 0.0f, bi_[4], bh_[4];
  if (tid < 256) {
#pragma unroll
    for (int q = 0; q < 4; q++) {
      size_t gi = (size_t)bo * GG + q * HID + en;
      vreg[q] = v0[gi];
      mreg[q] = m0[gi];
      bi_[q] = bih[q * HID + en];
      bh_[q] = bhh[q * HID + en];
    }
    creg = c0[(size_t)bo * HID + en];
  }
  __syncthreads();

  for (int t = 0; t < SEQL; ++t) {
    const _Float16* rh = (t & 1) ? hB_hi : hA_hi;
    const _Float16* rl = (t & 1) ? hB_lo : hA_lo;

    f32x4 aRM = {}, aRL = {}, aGM = {}, aGL = {};
    // recurrent GEMM: this wave's K-half of 1024 (weights from LDS)
#pragma unroll 4
    for (int kk = 0; kk < 512; kk += 32) {
      half8 ah = *(const half8*)(rh + hbase + kk);
      half8 al = *(const half8*)(rl + hbase + kk);
      half8 bh = *(const half8*)(Wp0 + lk_rec + kk);
      half8 bl = *(const half8*)(Wp1 + lk_rec + kk);
      aRM = mfma16(ah, bh, aRM);
      aRL = mfma16(al, bh, aRL);
      aRL = mfma16(ah, bl, aRL);
    }
    // input GEMM: K-half of 512, x split on the fly
    const float* xt = xbase + (size_t)t * INF;
#pragma unroll 2
    for (int kk = 0; kk < 256; kk += 32) {
      f32x4 x0 = *(const f32x4*)(xt + kk);
      f32x4 x1 = *(const f32x4*)(xt + kk + 4);
      half8 ah, al;
#pragma unroll
      for (int jj = 0; jj < 4; jj++) {
        _Float16 hi, lo;
        fsplit(x0[jj], hi, lo); ah[jj] = hi; al[jj] = lo;
        fsplit(x1[jj], hi, lo); ah[4 + jj] = hi; al[4 + jj] = lo;
      }
      half8 bh = *(const half8*)(Wp0 + lk_grad + kk);
      half8 bl = *(const half8*)(Wp1 + lk_grad + kk);
      aGM = mfma16(ah, bh, aGM);
      aGL = mfma16(al, bh, aGL);
      aGL = mfma16(ah, bl, aGL);
    }
    // combine split planes, publish partials
    f32x4 vR, vG;
#pragma unroll
    for (int i = 0; i < 4; i++) {
      vR[i] = aRM[i] + aRL[i] * ISCL;
      vG[i] = aGM[i] + aGL[i] * ISCL;
    }
    *(f32x4*)(ldsR + (size_t)(wave * 64 + lane) * 4) = vR;
    *(f32x4*)(ldsG + (size_t)(wave * 64 + lane) * 4) = vG;
    __syncthreads();

    if (tid < 256) {
      float gate[4];
#pragma unroll
      for (int q = 0; q < 4; q++) {
        int li = lg2 * 16 + q * 4 + j;
        float rec = ldsR[(size_t)((0 + bt2) * 64 + li) * 4 + rg] +
                    ldsR[(size_t)((4 + bt2) * 64 + li) * 4 + rg];
        float gr  = ldsG[(size_t)((0 + bt2) * 64 + li) * 4 + rg] +
                    ldsG[(size_t)((4 + bt2) * 64 + li) * 4 + rg] + bi_[q];
        vreg[q] = MU_ * vreg[q] + SSTEP_ * gr;
        mreg[q] = BETA_ * mreg[q] + (1.0f - BETA_) * gr * gr;
        gate[q] = vreg[q] / (sqrtf(mreg[q]) + EPS_) + rec + bh_[q];
      }
      float ig = 1.0f / (1.0f + expf(-gate[0]));
      float fg = 1.0f / (1.0f + expf(-gate[1]));
      float gg = tanhf(gate[2]);
      float og = 1.0f / (1.0f + expf(-gate[3]));
      creg = creg * fg + ig * gg;
      float hh = og * tanhf(creg);

      lout[(size_t)bo * (SEQL * HID) + (size_t)t * HID + en] = hh;
      _Float16 shi, slo;
      fsplit(hh, shi, slo);
      size_t hidx = (size_t)bo * HID + en;
      _Float16* wh = (t & 1) ? hA_hi : hB_hi;
      _Float16* wl = (t & 1) ? hA_lo : hB_lo;
      wh[hidx] = shi;
      wl[hidx] = slo;
      if (t == SEQL - 1) {
        hout[hidx] = hh;
        cout[hidx] = creg;
#pragma unroll
        for (int q = 0; q < 4; q++) {
          size_t gi = (size_t)bo * GG + q * HID + en;
          vout[gi] = vreg[q];
          mout[gi] = mreg[q];
        }
      }
      __threadfence();
    }
    grid.sync();
  }
}

extern "C" void kernel_launch(void* const* d_in, const int* in_sizes, int n_in,
                              void* d_out, int out_size, void* d_ws, size_t ws_size,
                              hipStream_t stream) {
  const float* x   = (const float*)d_in[0];
  const float* wih = (const float*)d_in[1];
  const float* whh = (const float*)d_in[2];
  const float* bih = (const float*)d_in[3];
  const float* bhh = (const float*)d_in[4];
  const float* h0  = (const float*)d_in[5];
  const float* c0  = (const float*)d_in[6];
  const float* v0  = (const float*)d_in[7];
  const float* m0  = (const float*)d_in[8];

  float* out  = (float*)d_out;
  float* lout = out;                                  // [B][S][H]
  float* hout = out + (size_t)BB * SEQL * HID;        // [B][H]
  float* cout = hout + (size_t)BB * HID;              // [B][H]
  float* vout = cout + (size_t)BB * HID;              // [B][G]
  float* mout = vout + (size_t)BB * GG;               // [B][G]

  char* ws = (char*)d_ws;
  size_t o = 0;
  _Float16* wih_hi = (_Float16*)(ws + o); o += (size_t)GG * INF * 2;   // 4 MiB
  _Float16* wih_lo = (_Float16*)(ws + o); o += (size_t)GG * INF * 2;   // 4 MiB
  _Float16* whh_hi = (_Float16*)(ws + o); o += (size_t)GG * HID * 2;   // 8 MiB
  _Float16* whh_lo = (_Float16*)(ws + o); o += (size_t)GG * HID * 2;   // 8 MiB
  _Float16* hA_hi  = (_Float16*)(ws + o); o += (size_t)BB * HID * 2;   // 128 KiB
  _Float16* hA_lo  = (_Float16*)(ws + o); o += (size_t)BB * HID * 2;
  _Float16* hB_hi  = (_Float16*)(ws + o); o += (size_t)BB * HID * 2;
  _Float16* hB_lo  = (_Float16*)(ws + o); o += (size_t)BB * HID * 2;

  transpose_split<<<dim3(GG / 32, INF / 32), 256, 0, stream>>>(wih, wih_hi, wih_lo, INF, GG);
  transpose_split<<<dim3(GG / 32, HID / 32), 256, 0, stream>>>(whh, whh_hi, whh_lo, HID, GG);
  init_h<<<(BB * HID) / 256, 256, 0, stream>>>(h0, hA_hi, hA_lo);

  void* args[] = {
    (void*)&x, (void*)&wih_hi, (void*)&wih_lo, (void*)&whh_hi, (void*)&whh_lo,
    (void*)&bih, (void*)&bhh, (void*)&v0, (void*)&m0, (void*)&c0,
    (void*)&hA_hi, (void*)&hA_lo, (void*)&hB_hi, (void*)&hB_lo,
    (void*)&lout, (void*)&hout, (void*)&cout, (void*)&vout, (void*)&mout,
  };
  hipLaunchCooperativeKernel(reinterpret_cast<void*>(rnn_persist),
                             dim3(256), dim3(512), args, SMEM_BYTES, stream);
}

// Round 6
// 23531.227 us; speedup vs baseline: 1.6399x; 1.5286x over previous
//
#include <hip/hip_runtime.h>
#include <cstdint>
#include <cstddef>

#define BB   64
#define SEQL 512
#define INF  512
#define HID  1024
#define GG   4096   // 4*HID

#define MU_    0.9f
#define SSTEP_ 0.1f
#define BETA_  0.999f
#define EPS_   1e-16f
#define SCL    2048.0f
#define ISCL   (1.0f / 2048.0f)

#define NWG   128
#define NTHR  1024
#define SMEM_BYTES (131072 + 8192)   // weights (frag order) + reduce buf

typedef unsigned short u16;
typedef unsigned int   u32;
typedef _Float16 half8 __attribute__((ext_vector_type(8)));
typedef float f32x4 __attribute__((ext_vector_type(4)));

__device__ __forceinline__ f32x4 mfma16(half8 a, half8 b, f32x4 c) {
  return __builtin_amdgcn_mfma_f32_16x16x32_f16(a, b, c, 0, 0, 0);
}
// f32 -> (hi, lo*2048) f16 split: x ~= hi + lo/2048, rel residual ~2^-22.
__device__ __forceinline__ void fsplit(float v, _Float16& hi, _Float16& lo) {
  hi = (_Float16)v;
  lo = (_Float16)((v - (float)hi) * SCL);
}
// device-coherent (cross-XCD) ops: compiler emits L2-bypassing access, no fences
__device__ __forceinline__ u32 coh_load(const u32* p) {
  return __hip_atomic_load(p, __ATOMIC_RELAXED, __HIP_MEMORY_SCOPE_AGENT);
}
__device__ __forceinline__ void coh_store(u32* p, u32 v) {
  __hip_atomic_store(p, v, __ATOMIC_RELAXED, __HIP_MEMORY_SCOPE_AGENT);
}

// ---- transpose + f16-split: src [R][C] f32 -> dhi/dlo [C][R] f16 ----
__global__ __launch_bounds__(256) void transpose_split(const float* __restrict__ src,
                                                       _Float16* __restrict__ dhi,
                                                       _Float16* __restrict__ dlo,
                                                       int R, int C) {
  __shared__ float tile[32][33];
  int c0 = blockIdx.x * 32, r0 = blockIdx.y * 32;
  int tx = threadIdx.x & 31, ty = threadIdx.x >> 5;  // 32 x 8
#pragma unroll
  for (int i = 0; i < 32; i += 8)
    tile[ty + i][tx] = src[(size_t)(r0 + ty + i) * C + (c0 + tx)];
  __syncthreads();
#pragma unroll
  for (int i = 0; i < 32; i += 8) {
    float v = tile[tx][ty + i];
    _Float16 hi, lo;
    fsplit(v, hi, lo);
    size_t o = (size_t)(c0 + ty + i) * R + (r0 + tx);
    dhi[o] = hi;
    dlo[o] = lo;
  }
}

// ---- init running state: vout<-v0, mout<-m0, cout<-c0, h0 -> split planes ----
__global__ __launch_bounds__(256) void init_state(const float* __restrict__ h0,
                                                  const float* __restrict__ c0,
                                                  const float* __restrict__ v0,
                                                  const float* __restrict__ m0,
                                                  float* __restrict__ co,
                                                  float* __restrict__ vo,
                                                  float* __restrict__ mo,
                                                  _Float16* __restrict__ hhi,
                                                  _Float16* __restrict__ hlo) {
  int i = blockIdx.x * 256 + threadIdx.x;
  if (i < BB * GG) { vo[i] = v0[i]; mo[i] = m0[i]; }
  if (i < BB * HID) {
    co[i] = c0[i];
    _Float16 hi, lo;
    fsplit(h0[i], hi, lo);
    hhi[i] = hi;
    hlo[i] = lo;
  }
}

// ---- grad chunk GEMM (f16-split, ~f32 accuracy), round-3-verified ----
// grad[tloc][b][g] = sum_k x[b][t][k]*W_ih[k][g] + b_ih[g]
__global__ __launch_bounds__(256) void grad_gemm(const float* __restrict__ x,
                                                 const _Float16* __restrict__ whi, // [G][IN]
                                                 const _Float16* __restrict__ wlo, // [G][IN]
                                                 const float* __restrict__ bih,
                                                 float* __restrict__ grad,         // [Tc][B][G]
                                                 int t0) {
  int tloc = blockIdx.x;
  int n0 = blockIdx.y * 64;
  int wave = threadIdx.x >> 6, lane = threadIdx.x & 63;
  int l15 = lane & 15, lg = lane >> 4;
  int t = t0 + tloc;
  int b = 16 * wave + l15;
  const float* xa = x + (size_t)b * (SEQL * INF) + (size_t)t * INF + lg * 8;
  const _Float16* wh = whi + (size_t)(n0 + l15) * INF + lg * 8;
  const _Float16* wl = wlo + (size_t)(n0 + l15) * INF + lg * 8;

  f32x4 accM[4] = {};
  f32x4 accL[4] = {};
  for (int kk = 0; kk < INF; kk += 32) {
    f32x4 x0 = *(const f32x4*)(xa + kk);
    f32x4 x1 = *(const f32x4*)(xa + kk + 4);
    half8 ah, al;
#pragma unroll
    for (int j = 0; j < 4; j++) {
      _Float16 hi, lo;
      fsplit(x0[j], hi, lo); ah[j] = hi; al[j] = lo;
      fsplit(x1[j], hi, lo); ah[4 + j] = hi; al[4 + j] = lo;
    }
#pragma unroll
    for (int nt = 0; nt < 4; nt++) {
      half8 bh = *(const half8*)(wh + (size_t)nt * 16 * INF + kk);
      half8 bl = *(const half8*)(wl + (size_t)nt * 16 * INF + kk);
      accM[nt] = mfma16(ah, bh, accM[nt]);
      accL[nt] = mfma16(al, bh, accL[nt]);
      accL[nt] = mfma16(ah, bl, accL[nt]);
    }
  }
#pragma unroll
  for (int nt = 0; nt < 4; nt++) {
    int g = n0 + nt * 16 + l15;
    float bias = bih[g];
#pragma unroll
    for (int r = 0; r < 4; r++) {
      int bo = 16 * wave + lg * 4 + r;
      grad[((size_t)tloc * BB + bo) * GG + g] = accM[nt][r] + accL[nt][r] * ISCL + bias;
    }
  }
}

// ---- momentum/second-moment scan: grad -> u = v'/(sqrt(m')+eps), in place ----
// thread = one (b,g); vst/mst are the running (and final-output) buffers.
__global__ __launch_bounds__(256) void scan_vm(float* __restrict__ grad,  // [T][B][G]
                                               float* __restrict__ vst,
                                               float* __restrict__ mst,
                                               int T) {
  int i = blockIdx.x * 256 + threadIdx.x;  // b*GG + g
  float v = vst[i], m = mst[i];
  for (int tt = 0; tt < T; ++tt) {
    size_t o = (size_t)tt * (BB * GG) + i;
    float g = grad[o];
    v = MU_ * v + SSTEP_ * g;
    m = BETA_ * m + (1.0f - BETA_) * g * g;
    grad[o] = v / (sqrtf(m) + EPS_);
  }
  vst[i] = v;
  mst[i] = m;
}

// ---- persistent recurrent kernel over a chunk of steps ----
// 128 wgs x 1024 thr (16 waves). wg nb owns cells nb*8..+7 (32 G-rows).
// W_hh (split) lives in LDS in FRAGMENT ORDER (linear per ds_read_b128).
// wave w: batch-tile bt=w>>2, K-quarter kq=w&3. Cross-XCD h handoff via
// device-scope relaxed atomics; barrier = vmcnt drain + counter.
__global__ __launch_bounds__(NTHR) void rnn_persist(
    const float* __restrict__ u,            // [T][B][G] preprocessed gates
    const _Float16* __restrict__ whh_hi,    // [G][H]
    const _Float16* __restrict__ whh_lo,
    const float* __restrict__ bhh,
    u32* __restrict__ hA_hi, u32* __restrict__ hA_lo,   // h planes as u32 pairs
    u32* __restrict__ hB_hi, u32* __restrict__ hB_lo,
    float* __restrict__ lout, float* __restrict__ hout,
    float* __restrict__ cout,               // running c (read at start, write at end)
    u32* __restrict__ ctr, int t0, int T) {
  extern __shared__ char smem[];
  _Float16* Wf = (_Float16*)smem;          // 131072 B, fragment order
  float* red = (float*)(smem + 131072);    // [4 bt][2 rt][16 col][16 brow] f32

  int tid = threadIdx.x;
  int wave = tid >> 6, lane = tid & 63;
  int l15 = lane & 15, lg = lane >> 4;
  int bt = wave >> 2, kq = wave & 3;
  int nb = blockIdx.x;

  // ---- stage W_hh slice into LDS in fragment order ----
  // slot s: lane=s&63; rest=s>>6; p=rest&1; rt=(rest>>1)&1; kk=(rest>>2)&7; kq2=rest>>5
  for (int s = tid; s < 8192; s += NTHR) {
    int ln = s & 63, rest = s >> 6;
    int p = rest & 1, rt = (rest >> 1) & 1, kk = (rest >> 2) & 7, kq2 = rest >> 5;
    int row = rt * 16 + (ln & 15);              // 0..31 = q*8+j
    int grow = (row >> 3) * HID + nb * 8 + (row & 7);
    int k = kq2 * 256 + kk * 32 + (ln >> 4) * 8;
    const _Float16* src = (p ? whh_lo : whh_hi) + (size_t)grow * HID + k;
    *(half8*)(Wf + (size_t)s * 8) = *(const half8*)src;
  }

  // epilogue constants: thread (bo, j), 512 threads
  int bo = tid >> 3, j = tid & 7;
  int within = bo & 15, btE = bo >> 4;
  float bh_[4], creg = 0.0f;
  if (tid < 512) {
#pragma unroll
    for (int q = 0; q < 4; q++) bh_[q] = bhh[q * HID + nb * 8 + j];
    creg = cout[(size_t)bo * HID + nb * 8 + j];
  }
  // h fragment base (u32 index): halves/2
  u32 hOffW = (u32)(((bt * 16 + l15) * HID + kq * 256 + lg * 8) >> 1);
  __syncthreads();

  for (int tt = 0; tt < T; ++tt) {
    int gt = t0 + tt;
    const u32* rhi = (gt & 1) ? hB_hi : hA_hi;
    const u32* rlo = (gt & 1) ? hB_lo : hA_lo;
    u32* whi = (gt & 1) ? hA_hi : hB_hi;
    u32* wlo = (gt & 1) ? hA_lo : hB_lo;

    // prefetch u for this step (plain loads; no cross-write during kernel)
    float uv[4];
    if (tid < 512) {
#pragma unroll
      for (int q = 0; q < 4; q++)
        uv[q] = u[((size_t)tt * BB + bo) * GG + q * HID + nb * 8 + j];
    }

    f32x4 aM0 = {}, aL0 = {}, aM1 = {}, aL1 = {};
#pragma unroll
    for (int kk = 0; kk < 8; ++kk) {
      union { u32 w[4]; half8 v; } ah, al;
#pragma unroll
      for (int i2 = 0; i2 < 4; ++i2) ah.w[i2] = coh_load(rhi + hOffW + kk * 16 + i2);
#pragma unroll
      for (int i2 = 0; i2 < 4; ++i2) al.w[i2] = coh_load(rlo + hOffW + kk * 16 + i2);
      const _Float16* wb = Wf + (size_t)((kq * 8 + kk) * 4) * 512 + lane * 8;
      half8 bh0 = *(const half8*)(wb);           // rt0, hi
      half8 bl0 = *(const half8*)(wb + 512);     // rt0, lo
      half8 bh1 = *(const half8*)(wb + 1024);    // rt1, hi
      half8 bl1 = *(const half8*)(wb + 1536);    // rt1, lo
      aM0 = mfma16(ah.v, bh0, aM0);
      aL0 = mfma16(al.v, bh0, aL0);
      aL0 = mfma16(ah.v, bl0, aL0);
      aM1 = mfma16(ah.v, bh1, aM1);
      aL1 = mfma16(al.v, bh1, aL1);
      aL1 = mfma16(ah.v, bl1, aL1);
    }
    // combine split planes
    f32x4 r0, r1;
#pragma unroll
    for (int i2 = 0; i2 < 4; ++i2) {
      r0[i2] = aM0[i2] + aL0[i2] * ISCL;
      r1[i2] = aM1[i2] + aL1[i2] * ISCL;
    }
    // reduce over kq: kq0 stores, others atomic-add
    if (kq == 0) {
#pragma unroll
      for (int i2 = 0; i2 < 4; ++i2) {
        red[((bt * 2 + 0) * 16 + l15) * 16 + lg * 4 + i2] = r0[i2];
        red[((bt * 2 + 1) * 16 + l15) * 16 + lg * 4 + i2] = r1[i2];
      }
    }
    __syncthreads();
    if (kq != 0) {
#pragma unroll
      for (int i2 = 0; i2 < 4; ++i2) {
        atomicAdd(&red[((bt * 2 + 0) * 16 + l15) * 16 + lg * 4 + i2], r0[i2]);
        atomicAdd(&red[((bt * 2 + 1) * 16 + l15) * 16 + lg * 4 + i2], r1[i2]);
      }
    }
    __syncthreads();

    if (tid < 512) {
      float gate[4];
#pragma unroll
      for (int q = 0; q < 4; q++) {
        int row = q * 8 + j, rt = row >> 4, col = row & 15;
        float rec = red[((btE * 2 + rt) * 16 + col) * 16 + within];
        gate[q] = uv[q] + rec + bh_[q];
      }
      float ig = 1.0f / (1.0f + expf(-gate[0]));
      float fg = 1.0f / (1.0f + expf(-gate[1]));
      float gg = tanhf(gate[2]);
      float og = 1.0f / (1.0f + expf(-gate[3]));
      creg = creg * fg + ig * gg;
      float hh = og * tanhf(creg);

      lout[((size_t)bo * SEQL + gt) * HID + nb * 8 + j] = hh;
      _Float16 shi, slo;
      fsplit(hh, shi, slo);
      union { _Float16 h; u16 b; } ch, cl;
      ch.h = shi; cl.h = slo;
      u32 myhi = ch.b, mylo = cl.b;
      u32 phi = __shfl_xor(myhi, 1);
      u32 plo = __shfl_xor(mylo, 1);
      if ((j & 1) == 0) {
        u32 off = (u32)(((size_t)bo * HID + nb * 8 + j) >> 1);
        coh_store(whi + off, myhi | (phi << 16));
        coh_store(wlo + off, mylo | (plo << 16));
      }
      if (gt == SEQL - 1) hout[(size_t)bo * HID + nb * 8 + j] = hh;
      if (tt == T - 1)    cout[(size_t)bo * HID + nb * 8 + j] = creg;
    }

    // flush-free grid barrier: drain own stores, then monotonic counter
    asm volatile("s_waitcnt vmcnt(0)" ::: "memory");
    __syncthreads();
    if (tid == 0) {
      __hip_atomic_fetch_add(ctr, 1u, __ATOMIC_RELAXED, __HIP_MEMORY_SCOPE_AGENT);
      u32 target = (u32)gridDim.x * (u32)(tt + 1);
      while (__hip_atomic_load(ctr, __ATOMIC_RELAXED, __HIP_MEMORY_SCOPE_AGENT) < target)
        __builtin_amdgcn_s_sleep(2);
    }
    __syncthreads();
  }
}

extern "C" void kernel_launch(void* const* d_in, const int* in_sizes, int n_in,
                              void* d_out, int out_size, void* d_ws, size_t ws_size,
                              hipStream_t stream) {
  const float* x   = (const float*)d_in[0];
  const float* wih = (const float*)d_in[1];
  const float* whh = (const float*)d_in[2];
  const float* bih = (const float*)d_in[3];
  const float* bhh = (const float*)d_in[4];
  const float* h0  = (const float*)d_in[5];
  const float* c0  = (const float*)d_in[6];
  const float* v0  = (const float*)d_in[7];
  const float* m0  = (const float*)d_in[8];

  float* out  = (float*)d_out;
  float* lout = out;                                  // [B][S][H]
  float* hout = out + (size_t)BB * SEQL * HID;        // [B][H]
  float* cout = hout + (size_t)BB * HID;              // [B][H] (also running c)
  float* vout = cout + (size_t)BB * HID;              // [B][G] (also running v)
  float* mout = vout + (size_t)BB * GG;               // [B][G] (also running m)

  char* ws = (char*)d_ws;
  size_t o = 0;
  _Float16* wih_hi = (_Float16*)(ws + o); o += (size_t)GG * INF * 2;   // 4 MiB
  _Float16* wih_lo = (_Float16*)(ws + o); o += (size_t)GG * INF * 2;   // 4 MiB
  _Float16* whh_hi = (_Float16*)(ws + o); o += (size_t)GG * HID * 2;   // 8 MiB
  _Float16* whh_lo = (_Float16*)(ws + o); o += (size_t)GG * HID * 2;   // 8 MiB
  _Float16* hA_hi  = (_Float16*)(ws + o); o += (size_t)BB * HID * 2;   // 128 KiB
  _Float16* hA_lo  = (_Float16*)(ws + o); o += (size_t)BB * HID * 2;
  _Float16* hB_hi  = (_Float16*)(ws + o); o += (size_t)BB * HID * 2;
  _Float16* hB_lo  = (_Float16*)(ws + o); o += (size_t)BB * HID * 2;
  o = (o + 255) & ~(size_t)255;
  u32* ctr = (u32*)(ws + o); o += 256;
  float* U = (float*)(ws + o);

  const size_t STEP_BYTES = (size_t)BB * GG * sizeof(float);  // 1 MiB
  size_t cap = (ws_size > o) ? (ws_size - o) / STEP_BYTES : 1;
  if (cap < 1) cap = 1;
  int Tc = (int)(cap < (size_t)SEQL ? cap : (size_t)SEQL);

  transpose_split<<<dim3(GG / 32, INF / 32), 256, 0, stream>>>(wih, wih_hi, wih_lo, INF, GG);
  transpose_split<<<dim3(GG / 32, HID / 32), 256, 0, stream>>>(whh, whh_hi, whh_lo, HID, GG);
  init_state<<<(BB * GG) / 256, 256, 0, stream>>>(h0, c0, v0, m0, cout, vout, mout, hA_hi, hA_lo);

  for (int t0 = 0; t0 < SEQL; t0 += Tc) {
    int T = (SEQL - t0 < Tc) ? (SEQL - t0) : Tc;
    grad_gemm<<<dim3(T, GG / 64), 256, 0, stream>>>(x, wih_hi, wih_lo, bih, U, t0);
    scan_vm<<<(BB * GG) / 256, 256, 0, stream>>>(U, vout, mout, T);
    hipMemsetAsync(ctr, 0, 4, stream);
    rnn_persist<<<NWG, NTHR, SMEM_BYTES, stream>>>(
        U, whh_hi, whh_lo, bhh,
        (u32*)hA_hi, (u32*)hA_lo, (u32*)hB_hi, (u32*)hB_lo,
        lout, hout, cout, ctr, t0, T);
  }
}

// Round 7
// 11733.989 us; speedup vs baseline: 3.2887x; 2.0054x over previous
//
#include <hip/hip_runtime.h>
#include <cstdint>
#include <cstddef>

#define BB   64
#define SEQL 512
#define INF  512
#define HID  1024
#define GG   4096   // 4*HID

#define MU_    0.9f
#define SSTEP_ 0.1f
#define BETA_  0.999f
#define EPS_   1e-16f
#define SCL    2048.0f
#define ISCL   (1.0f / 2048.0f)

#define NWG   128
#define NTHR  1024
#define WLDS  131072                     // weights, frag order
#define RLDS  16384                      // reduce slots
#define SMEM_BYTES (WLDS + RLDS)         // 147456 <= 160 KiB

typedef unsigned short u16;
typedef unsigned int   u32;
typedef unsigned long long u64;
typedef _Float16 half8 __attribute__((ext_vector_type(8)));
typedef float f32x4 __attribute__((ext_vector_type(4)));

__device__ __forceinline__ f32x4 mfma16(half8 a, half8 b, f32x4 c) {
  return __builtin_amdgcn_mfma_f32_16x16x32_f16(a, b, c, 0, 0, 0);
}
__device__ __forceinline__ void fsplit(float v, _Float16& hi, _Float16& lo) {
  hi = (_Float16)v;
  lo = (_Float16)((v - (float)hi) * SCL);
}
// device-coherent (cross-XCD) ops — bypass non-coherent per-XCD L2
__device__ __forceinline__ u32 coh_load32(const u32* p) {
  return __hip_atomic_load(p, __ATOMIC_RELAXED, __HIP_MEMORY_SCOPE_AGENT);
}
__device__ __forceinline__ void coh_store32(u32* p, u32 v) {
  __hip_atomic_store(p, v, __ATOMIC_RELAXED, __HIP_MEMORY_SCOPE_AGENT);
}
__device__ __forceinline__ u64 coh_load64(const u64* p) {
  return __hip_atomic_load(p, __ATOMIC_RELAXED, __HIP_MEMORY_SCOPE_AGENT);
}
__device__ __forceinline__ void coh_store64(u64* p, u64 v) {
  __hip_atomic_store(p, v, __ATOMIC_RELAXED, __HIP_MEMORY_SCOPE_AGENT);
}

// ---- transpose + f16-split: src [R][C] f32 -> dhi/dlo [C][R] f16 ----
__global__ __launch_bounds__(256) void transpose_split(const float* __restrict__ src,
                                                       _Float16* __restrict__ dhi,
                                                       _Float16* __restrict__ dlo,
                                                       int R, int C) {
  __shared__ float tile[32][33];
  int c0 = blockIdx.x * 32, r0 = blockIdx.y * 32;
  int tx = threadIdx.x & 31, ty = threadIdx.x >> 5;
#pragma unroll
  for (int i = 0; i < 32; i += 8)
    tile[ty + i][tx] = src[(size_t)(r0 + ty + i) * C + (c0 + tx)];
  __syncthreads();
#pragma unroll
  for (int i = 0; i < 32; i += 8) {
    float v = tile[tx][ty + i];
    _Float16 hi, lo;
    fsplit(v, hi, lo);
    size_t o = (size_t)(c0 + ty + i) * R + (r0 + tx);
    dhi[o] = hi;
    dlo[o] = lo;
  }
}

// ---- init running state ----
__global__ __launch_bounds__(256) void init_state(const float* __restrict__ h0,
                                                  const float* __restrict__ c0,
                                                  const float* __restrict__ v0,
                                                  const float* __restrict__ m0,
                                                  float* __restrict__ co,
                                                  float* __restrict__ vo,
                                                  float* __restrict__ mo,
                                                  _Float16* __restrict__ hhi,
                                                  _Float16* __restrict__ hlo) {
  int i = blockIdx.x * 256 + threadIdx.x;
  if (i < BB * GG) { vo[i] = v0[i]; mo[i] = m0[i]; }
  if (i < BB * HID) {
    co[i] = c0[i];
    _Float16 hi, lo;
    fsplit(h0[i], hi, lo);
    hhi[i] = hi;
    hlo[i] = lo;
  }
}

// ---- grad chunk GEMM (f16-split), 128-col tiles ----
__global__ __launch_bounds__(256) void grad_gemm(const float* __restrict__ x,
                                                 const _Float16* __restrict__ whi,
                                                 const _Float16* __restrict__ wlo,
                                                 const float* __restrict__ bih,
                                                 float* __restrict__ grad,  // [Tc][B][G]
                                                 int t0) {
  int tloc = blockIdx.x;
  int n0 = blockIdx.y * 128;
  int wave = threadIdx.x >> 6, lane = threadIdx.x & 63;
  int l15 = lane & 15, lg = lane >> 4;
  int t = t0 + tloc;
  int b = 16 * wave + l15;
  const float* xa = x + (size_t)b * (SEQL * INF) + (size_t)t * INF + lg * 8;
  const _Float16* wh = whi + (size_t)(n0 + l15) * INF + lg * 8;
  const _Float16* wl = wlo + (size_t)(n0 + l15) * INF + lg * 8;

  f32x4 accM[8] = {};
  f32x4 accL[8] = {};
  for (int kk = 0; kk < INF; kk += 32) {
    f32x4 x0 = *(const f32x4*)(xa + kk);
    f32x4 x1 = *(const f32x4*)(xa + kk + 4);
    half8 ah, al;
#pragma unroll
    for (int j = 0; j < 4; j++) {
      _Float16 hi, lo;
      fsplit(x0[j], hi, lo); ah[j] = hi; al[j] = lo;
      fsplit(x1[j], hi, lo); ah[4 + j] = hi; al[4 + j] = lo;
    }
#pragma unroll
    for (int nt = 0; nt < 8; nt++) {
      half8 bh = *(const half8*)(wh + (size_t)nt * 16 * INF + kk);
      half8 bl = *(const half8*)(wl + (size_t)nt * 16 * INF + kk);
      accM[nt] = mfma16(ah, bh, accM[nt]);
      accL[nt] = mfma16(al, bh, accL[nt]);
      accL[nt] = mfma16(ah, bl, accL[nt]);
    }
  }
#pragma unroll
  for (int nt = 0; nt < 8; nt++) {
    int g = n0 + nt * 16 + l15;
    float bias = bih[g];
#pragma unroll
    for (int r = 0; r < 4; r++) {
      int bo = 16 * wave + lg * 4 + r;
      grad[((size_t)tloc * BB + bo) * GG + g] = accM[nt][r] + accL[nt][r] * ISCL + bias;
    }
  }
}

// ---- momentum/second-moment scan: grad -> u = v'/(sqrt(m')+eps), in place ----
__global__ __launch_bounds__(256) void scan_vm(float* __restrict__ grad,
                                               float* __restrict__ vst,
                                               float* __restrict__ mst,
                                               int T) {
  int i = blockIdx.x * 256 + threadIdx.x;
  float v = vst[i], m = mst[i];
  for (int tt = 0; tt < T; ++tt) {
    size_t o = (size_t)tt * (BB * GG) + i;
    float g = grad[o];
    v = MU_ * v + SSTEP_ * g;
    m = BETA_ * m + (1.0f - BETA_) * g * g;
    grad[o] = v / (sqrtf(m) + EPS_);
  }
  vst[i] = v;
  mst[i] = m;
}

// ---- persistent recurrent kernel ----
// 128 wgs x 1024 thr (16 waves). wg nb owns cells nb*8..+7 (32 G-rows).
// W_hh split lives in LDS (frag order). wave w: bt=w>>2 (16 batch rows),
// kq=w&3 (K quarter). h exchange: batched u64 AGENT atomic loads/stores.
// Barrier: per-wg padded flags + all-wg read-only poll (no RMW hotspot).
__global__ __launch_bounds__(NTHR, 1) void rnn_persist(
    const float* __restrict__ u,          // [T][B][G]
    const _Float16* __restrict__ whh_hi, const _Float16* __restrict__ whh_lo,
    const float* __restrict__ bhh,
    u64* __restrict__ hA_hi, u64* __restrict__ hA_lo,
    u64* __restrict__ hB_hi, u64* __restrict__ hB_lo,
    float* __restrict__ lout, float* __restrict__ hout,
    float* __restrict__ cout, u32* __restrict__ flags, int t0, int T) {
  extern __shared__ char smem[];
  _Float16* Wf = (_Float16*)smem;        // 128 KiB frag-order weights
  float* red = (float*)(smem + WLDS);    // [bt4][kqh2][rt2][col16][brow16]

  int tid = threadIdx.x;
  int wave = tid >> 6, lane = tid & 63;
  int l15 = lane & 15, lg = lane >> 4;
  int bt = wave >> 2, kq = wave & 3;
  int nb = blockIdx.x;

  // ---- stage W_hh slice into LDS in fragment order ----
  for (int s = tid; s < 8192; s += NTHR) {
    int ln = s & 63, rest = s >> 6;
    int p = rest & 1, rt = (rest >> 1) & 1, kk = (rest >> 2) & 7, kq2 = rest >> 5;
    int row = rt * 16 + (ln & 15);
    int grow = (row >> 3) * HID + nb * 8 + (row & 7);
    int k = kq2 * 256 + kk * 32 + (ln >> 4) * 8;
    const _Float16* src = (p ? whh_lo : whh_hi) + (size_t)grow * HID + k;
    *(half8*)(Wf + (size_t)s * 8) = *(const half8*)src;
  }

  // epilogue constants (tid<512): thread = (batch bo, cell j)
  int bo = tid >> 3, j = tid & 7;
  int within = bo & 15, btE = bo >> 4;
  float bh_[4], creg = 0.0f, uv[4] = {};
  if (tid < 512) {
#pragma unroll
    for (int q = 0; q < 4; q++) bh_[q] = bhh[q * HID + nb * 8 + j];
    creg = cout[(size_t)bo * HID + nb * 8 + j];
#pragma unroll
    for (int q = 0; q < 4; q++)
      uv[q] = u[(size_t)bo * GG + q * HID + nb * 8 + j];  // tt=0 prefetch
  }
  // h fragment base (u64 index)
  u32 hB = (u32)((((bt * 16 + l15) * HID) + kq * 256 + lg * 8) >> 2);
  __syncthreads();

  for (int tt = 0; tt < T; ++tt) {
    int gt = t0 + tt;
    const u64* rhi = (gt & 1) ? hB_hi : hA_hi;
    const u64* rlo = (gt & 1) ? hB_lo : hA_lo;
    u64* whi = (gt & 1) ? hA_hi : hB_hi;
    u64* wlo = (gt & 1) ? hA_lo : hB_lo;

    // ---- batched h loads: 32 independent u64 coherent loads, no uses between
    u64 hH[16], hL[16];
#pragma unroll
    for (int kk = 0; kk < 8; ++kk) {
      hH[2 * kk]     = coh_load64(rhi + hB + kk * 8);
      hH[2 * kk + 1] = coh_load64(rhi + hB + kk * 8 + 1);
    }
#pragma unroll
    for (int kk = 0; kk < 8; ++kk) {
      hL[2 * kk]     = coh_load64(rlo + hB + kk * 8);
      hL[2 * kk + 1] = coh_load64(rlo + hB + kk * 8 + 1);
    }

    f32x4 aM0 = {}, aL0 = {}, aM1 = {}, aL1 = {};
#pragma unroll
    for (int kk = 0; kk < 8; ++kk) {
      union { u64 q[2]; half8 v; } ah, al;
      ah.q[0] = hH[2 * kk]; ah.q[1] = hH[2 * kk + 1];
      al.q[0] = hL[2 * kk]; al.q[1] = hL[2 * kk + 1];
      const _Float16* wb = Wf + (size_t)((kq * 8 + kk) * 4) * 512 + lane * 8;
      half8 bh0 = *(const half8*)(wb);
      half8 bl0 = *(const half8*)(wb + 512);
      half8 bh1 = *(const half8*)(wb + 1024);
      half8 bl1 = *(const half8*)(wb + 1536);
      aM0 = mfma16(ah.v, bh0, aM0);
      aL0 = mfma16(al.v, bh0, aL0);
      aL0 = mfma16(ah.v, bl0, aL0);
      aM1 = mfma16(ah.v, bh1, aM1);
      aL1 = mfma16(al.v, bh1, aL1);
      aL1 = mfma16(ah.v, bl1, aL1);
    }
    f32x4 r0, r1;
#pragma unroll
    for (int i2 = 0; i2 < 4; ++i2) {
      r0[i2] = aM0[i2] + aL0[i2] * ISCL;
      r1[i2] = aM1[i2] + aL1[i2] * ISCL;
    }

    // ---- pairwise kq reduce in LDS (no atomics) ----
    int kqh = kq >> 1;
    int s0 = ((bt * 2 + kqh) * 2 + 0) * 256 + l15 * 16 + lg * 4;
    int s1 = ((bt * 2 + kqh) * 2 + 1) * 256 + l15 * 16 + lg * 4;
    if (kq & 1) {
      *(f32x4*)(red + s0) = r0;
      *(f32x4*)(red + s1) = r1;
    }
    __syncthreads();
    if (!(kq & 1)) {
      *(f32x4*)(red + s0) = r0 + *(const f32x4*)(red + s0);
      *(f32x4*)(red + s1) = r1 + *(const f32x4*)(red + s1);
    }
    // prefetch next step's u (overlaps barrier)
    float uvN[4] = {};
    if (tid < 512 && tt + 1 < T) {
#pragma unroll
      for (int q = 0; q < 4; q++)
        uvN[q] = u[((size_t)(tt + 1) * BB + bo) * GG + q * HID + nb * 8 + j];
    }
    __syncthreads();

    if (tid < 512) {
      float gate[4];
#pragma unroll
      for (int q = 0; q < 4; q++) {
        int row = q * 8 + j, rt = row >> 4, col = row & 15;
        float rec = red[((btE * 2 + 0) * 2 + rt) * 256 + col * 16 + within] +
                    red[((btE * 2 + 1) * 2 + rt) * 256 + col * 16 + within];
        gate[q] = uv[q] + rec + bh_[q];
      }
      float ig = 1.0f / (1.0f + expf(-gate[0]));
      float fg = 1.0f / (1.0f + expf(-gate[1]));
      float gg = tanhf(gate[2]);
      float og = 1.0f / (1.0f + expf(-gate[3]));
      creg = creg * fg + ig * gg;
      float hh = og * tanhf(creg);

      lout[((size_t)bo * SEQL + gt) * HID + nb * 8 + j] = hh;
      _Float16 shi, slo;
      fsplit(hh, shi, slo);
      union { _Float16 h; u16 b; } ch, cl;
      ch.h = shi; cl.h = slo;
      u32 myh = ch.b, myl = cl.b;
      u32 oh = __shfl_xor(myh, 1), ol = __shfl_xor(myl, 1);
      u32 ph = (j & 1) ? (oh | (myh << 16)) : (myh | (oh << 16));
      u32 pl = (j & 1) ? (ol | (myl << 16)) : (myl | (ol << 16));
      u32 qh = __shfl_xor(ph, 2), ql = __shfl_xor(pl, 2);
      if ((j & 3) == 0) {
        u32 off = (u32)(((size_t)bo * HID + nb * 8 + j) >> 2);
        coh_store64(whi + off, (u64)ph | ((u64)qh << 32));
        coh_store64(wlo + off, (u64)pl | ((u64)ql << 32));
      }
      if (gt == SEQL - 1) hout[(size_t)bo * HID + nb * 8 + j] = hh;
      if (tt == T - 1)    cout[(size_t)bo * HID + nb * 8 + j] = creg;
#pragma unroll
      for (int q = 0; q < 4; q++) uv[q] = uvN[q];
    }

    if (tt + 1 < T) {
      // drain own stores (per-wave), then signal + poll (contention-free)
      asm volatile("s_waitcnt vmcnt(0)" ::: "memory");
      __syncthreads();
      u32 target = (u32)(t0 + tt + 1);
      if (tid == 0) coh_store32(flags + nb * 32, target);
      if (wave == 0) {
        const u32* f0 = flags + (2 * lane) * 32;
        const u32* f1 = flags + (2 * lane + 1) * 32;
        while (!__all(coh_load32(f0) >= target && coh_load32(f1) >= target))
          __builtin_amdgcn_s_sleep(1);
      }
      __syncthreads();
    }
  }
}

extern "C" void kernel_launch(void* const* d_in, const int* in_sizes, int n_in,
                              void* d_out, int out_size, void* d_ws, size_t ws_size,
                              hipStream_t stream) {
  const float* x   = (const float*)d_in[0];
  const float* wih = (const float*)d_in[1];
  const float* whh = (const float*)d_in[2];
  const float* bih = (const float*)d_in[3];
  const float* bhh = (const float*)d_in[4];
  const float* h0  = (const float*)d_in[5];
  const float* c0  = (const float*)d_in[6];
  const float* v0  = (const float*)d_in[7];
  const float* m0  = (const float*)d_in[8];

  float* out  = (float*)d_out;
  float* lout = out;
  float* hout = out + (size_t)BB * SEQL * HID;
  float* cout = hout + (size_t)BB * HID;   // running c
  float* vout = cout + (size_t)BB * HID;   // running v
  float* mout = vout + (size_t)BB * GG;    // running m

  char* ws = (char*)d_ws;
  size_t o = 0;
  _Float16* wih_hi = (_Float16*)(ws + o); o += (size_t)GG * INF * 2;
  _Float16* wih_lo = (_Float16*)(ws + o); o += (size_t)GG * INF * 2;
  _Float16* whh_hi = (_Float16*)(ws + o); o += (size_t)GG * HID * 2;
  _Float16* whh_lo = (_Float16*)(ws + o); o += (size_t)GG * HID * 2;
  _Float16* hA_hi  = (_Float16*)(ws + o); o += (size_t)BB * HID * 2;
  _Float16* hA_lo  = (_Float16*)(ws + o); o += (size_t)BB * HID * 2;
  _Float16* hB_hi  = (_Float16*)(ws + o); o += (size_t)BB * HID * 2;
  _Float16* hB_lo  = (_Float16*)(ws + o); o += (size_t)BB * HID * 2;
  o = (o + 255) & ~(size_t)255;
  u32* flags = (u32*)(ws + o); o += (size_t)NWG * 32 * 4;
  float* U = (float*)(ws + o);

  const size_t STEP_BYTES = (size_t)BB * GG * sizeof(float);
  size_t cap = (ws_size > o) ? (ws_size - o) / STEP_BYTES : 1;
  if (cap < 1) cap = 1;
  int Tc = (int)(cap < (size_t)SEQL ? cap : (size_t)SEQL);

  transpose_split<<<dim3(GG / 32, INF / 32), 256, 0, stream>>>(wih, wih_hi, wih_lo, INF, GG);
  transpose_split<<<dim3(GG / 32, HID / 32), 256, 0, stream>>>(whh, whh_hi, whh_lo, HID, GG);
  init_state<<<(BB * GG) / 256, 256, 0, stream>>>(h0, c0, v0, m0, cout, vout, mout, hA_hi, hA_lo);
  hipMemsetAsync(flags, 0, (size_t)NWG * 32 * 4, stream);

  for (int t0 = 0; t0 < SEQL; t0 += Tc) {
    int T = (SEQL - t0 < Tc) ? (SEQL - t0) : Tc;
    grad_gemm<<<dim3(T, GG / 128), 256, 0, stream>>>(x, wih_hi, wih_lo, bih, U, t0);
    scan_vm<<<(BB * GG) / 256, 256, 0, stream>>>(U, vout, mout, T);
    rnn_persist<<<NWG, NTHR, SMEM_BYTES, stream>>>(
        U, whh_hi, whh_lo, bhh,
        (u64*)hA_hi, (u64*)hA_lo, (u64*)hB_hi, (u64*)hB_lo,
        lout, hout, cout, flags, t0, T);
  }
}

// Round 8
// 11425.504 us; speedup vs baseline: 3.3775x; 1.0270x over previous
//
#include <hip/hip_runtime.h>
#include <cstdint>
#include <cstddef>

#define BB   64
#define SEQL 512
#define INF  512
#define HID  1024
#define GG   4096   // 4*HID

#define MU_    0.9f
#define SSTEP_ 0.1f
#define BETA_  0.999f
#define EPS_   1e-16f
#define SCL    2048.0f
#define ISCL   (1.0f / 2048.0f)

#define NWG   128
#define NTHR  1024
#define WLDS  131072                     // weights, frag order
#define RLDS  16384                      // reduce slots
#define HPKB  2048                       // h pack buffer (2 planes x 512 halves)
#define SMEM_BYTES (WLDS + RLDS + HPKB)  // 149504 <= 160 KiB

typedef unsigned short u16;
typedef unsigned int   u32;
typedef unsigned long long u64;
typedef _Float16 half8 __attribute__((ext_vector_type(8)));
typedef float f32x4 __attribute__((ext_vector_type(4)));
typedef u32 u32x4 __attribute__((ext_vector_type(4)));

__device__ __forceinline__ f32x4 mfma16(half8 a, half8 b, f32x4 c) {
  return __builtin_amdgcn_mfma_f32_16x16x32_f16(a, b, c, 0, 0, 0);
}
__device__ __forceinline__ void fsplit(float v, _Float16& hi, _Float16& lo) {
  hi = (_Float16)v;
  lo = (_Float16)((v - (float)hi) * SCL);
}
// device-coherent (cross-XCD) atomic ops for control & h stores (proven path)
__device__ __forceinline__ u32 coh_load32(const u32* p) {
  return __hip_atomic_load(p, __ATOMIC_RELAXED, __HIP_MEMORY_SCOPE_AGENT);
}
__device__ __forceinline__ void coh_store32(u32* p, u32 v) {
  __hip_atomic_store(p, v, __ATOMIC_RELAXED, __HIP_MEMORY_SCOPE_AGENT);
}
__device__ __forceinline__ void coh_store64(u64* p, u64 v) {
  __hip_atomic_store(p, v, __ATOMIC_RELAXED, __HIP_MEMORY_SCOPE_AGENT);
}

// 8 batched device-coherent 16B loads from base addr (+ kk*64B), one asm block:
// un-sinkable, un-splittable. Values valid only after s_waitcnt vmcnt.
#define GLD8(o0,o1,o2,o3,o4,o5,o6,o7,addr)                      \
  asm volatile(                                                 \
    "global_load_dwordx4 %0, %8, off sc0 sc1\n\t"               \
    "global_load_dwordx4 %1, %8, off offset:64 sc0 sc1\n\t"     \
    "global_load_dwordx4 %2, %8, off offset:128 sc0 sc1\n\t"    \
    "global_load_dwordx4 %3, %8, off offset:192 sc0 sc1\n\t"    \
    "global_load_dwordx4 %4, %8, off offset:256 sc0 sc1\n\t"    \
    "global_load_dwordx4 %5, %8, off offset:320 sc0 sc1\n\t"    \
    "global_load_dwordx4 %6, %8, off offset:384 sc0 sc1\n\t"    \
    "global_load_dwordx4 %7, %8, off offset:448 sc0 sc1"        \
    : "=&v"(o0), "=&v"(o1), "=&v"(o2), "=&v"(o3),               \
      "=&v"(o4), "=&v"(o5), "=&v"(o6), "=&v"(o7)                \
    : "v"(addr))

// ---- transpose + f16-split: src [R][C] f32 -> dhi/dlo [C][R] f16 ----
__global__ __launch_bounds__(256) void transpose_split(const float* __restrict__ src,
                                                       _Float16* __restrict__ dhi,
                                                       _Float16* __restrict__ dlo,
                                                       int R, int C) {
  __shared__ float tile[32][33];
  int c0 = blockIdx.x * 32, r0 = blockIdx.y * 32;
  int tx = threadIdx.x & 31, ty = threadIdx.x >> 5;
#pragma unroll
  for (int i = 0; i < 32; i += 8)
    tile[ty + i][tx] = src[(size_t)(r0 + ty + i) * C + (c0 + tx)];
  __syncthreads();
#pragma unroll
  for (int i = 0; i < 32; i += 8) {
    float v = tile[tx][ty + i];
    _Float16 hi, lo;
    fsplit(v, hi, lo);
    size_t o = (size_t)(c0 + ty + i) * R + (r0 + tx);
    dhi[o] = hi;
    dlo[o] = lo;
  }
}

// ---- init running state ----
__global__ __launch_bounds__(256) void init_state(const float* __restrict__ h0,
                                                  const float* __restrict__ c0,
                                                  const float* __restrict__ v0,
                                                  const float* __restrict__ m0,
                                                  float* __restrict__ co,
                                                  float* __restrict__ vo,
                                                  float* __restrict__ mo,
                                                  _Float16* __restrict__ hhi,
                                                  _Float16* __restrict__ hlo) {
  int i = blockIdx.x * 256 + threadIdx.x;
  if (i < BB * GG) { vo[i] = v0[i]; mo[i] = m0[i]; }
  if (i < BB * HID) {
    co[i] = c0[i];
    _Float16 hi, lo;
    fsplit(h0[i], hi, lo);
    hhi[i] = hi;
    hlo[i] = lo;
  }
}

// ---- grad chunk GEMM (f16-split), 128-col tiles ----
__global__ __launch_bounds__(256) void grad_gemm(const float* __restrict__ x,
                                                 const _Float16* __restrict__ whi,
                                                 const _Float16* __restrict__ wlo,
                                                 const float* __restrict__ bih,
                                                 float* __restrict__ grad,  // [Tc][B][G]
                                                 int t0) {
  int tloc = blockIdx.x;
  int n0 = blockIdx.y * 128;
  int wave = threadIdx.x >> 6, lane = threadIdx.x & 63;
  int l15 = lane & 15, lg = lane >> 4;
  int t = t0 + tloc;
  int b = 16 * wave + l15;
  const float* xa = x + (size_t)b * (SEQL * INF) + (size_t)t * INF + lg * 8;
  const _Float16* wh = whi + (size_t)(n0 + l15) * INF + lg * 8;
  const _Float16* wl = wlo + (size_t)(n0 + l15) * INF + lg * 8;

  f32x4 accM[8] = {};
  f32x4 accL[8] = {};
  for (int kk = 0; kk < INF; kk += 32) {
    f32x4 x0 = *(const f32x4*)(xa + kk);
    f32x4 x1 = *(const f32x4*)(xa + kk + 4);
    half8 ah, al;
#pragma unroll
    for (int j = 0; j < 4; j++) {
      _Float16 hi, lo;
      fsplit(x0[j], hi, lo); ah[j] = hi; al[j] = lo;
      fsplit(x1[j], hi, lo); ah[4 + j] = hi; al[4 + j] = lo;
    }
#pragma unroll
    for (int nt = 0; nt < 8; nt++) {
      half8 bh = *(const half8*)(wh + (size_t)nt * 16 * INF + kk);
      half8 bl = *(const half8*)(wl + (size_t)nt * 16 * INF + kk);
      accM[nt] = mfma16(ah, bh, accM[nt]);
      accL[nt] = mfma16(al, bh, accL[nt]);
      accL[nt] = mfma16(ah, bl, accL[nt]);
    }
  }
#pragma unroll
  for (int nt = 0; nt < 8; nt++) {
    int g = n0 + nt * 16 + l15;
    float bias = bih[g];
#pragma unroll
    for (int r = 0; r < 4; r++) {
      int bo = 16 * wave + lg * 4 + r;
      grad[((size_t)tloc * BB + bo) * GG + g] = accM[nt][r] + accL[nt][r] * ISCL + bias;
    }
  }
}

// ---- momentum/second-moment scan: grad -> u = v'/(sqrt(m')+eps), in place ----
__global__ __launch_bounds__(256) void scan_vm(float* __restrict__ grad,
                                               float* __restrict__ vst,
                                               float* __restrict__ mst,
                                               int T) {
  int i = blockIdx.x * 256 + threadIdx.x;
  float v = vst[i], m = mst[i];
  for (int tt = 0; tt < T; ++tt) {
    size_t o = (size_t)tt * (BB * GG) + i;
    float g = grad[o];
    v = MU_ * v + SSTEP_ * g;
    m = BETA_ * m + (1.0f - BETA_) * g * g;
    grad[o] = v / (sqrtf(m) + EPS_);
  }
  vst[i] = v;
  mst[i] = m;
}

// ---- persistent recurrent kernel ----
// 128 wgs x 1024 thr (16 waves). wg nb owns cells nb*8..+7 (32 G-rows).
// W_hh split in LDS (frag order). wave w: bt=w>>2 (16 batch rows), kq=w&3.
// h exchange: asm-batched coherent dwordx4 loads (2 phases), LDS-packed
// coherent u64 stores. Barrier: per-wg padded flags + read-only poll.
__global__ __launch_bounds__(NTHR, 1) void rnn_persist(
    const float* __restrict__ u,          // [T][B][G]
    const _Float16* __restrict__ whh_hi, const _Float16* __restrict__ whh_lo,
    const float* __restrict__ bhh,
    _Float16* __restrict__ hA_hi, _Float16* __restrict__ hA_lo,
    _Float16* __restrict__ hB_hi, _Float16* __restrict__ hB_lo,
    float* __restrict__ lout, float* __restrict__ hout,
    float* __restrict__ cout, u32* __restrict__ flags, int t0, int T) {
  extern __shared__ char smem[];
  _Float16* Wf = (_Float16*)smem;                 // 128 KiB frag-order weights
  float* red = (float*)(smem + WLDS);             // reduce: [bt4][kqh2][rt2][16][16]
  u16* hpk = (u16*)(smem + WLDS + RLDS);          // [2][512] packed h halves

  int tid = threadIdx.x;
  int wave = tid >> 6, lane = tid & 63;
  int l15 = lane & 15, lg = lane >> 4;
  int bt = wave >> 2, kq = wave & 3;
  int nb = blockIdx.x;

  // ---- stage W_hh slice into LDS in fragment order ----
  for (int s = tid; s < 8192; s += NTHR) {
    int ln = s & 63, rest = s >> 6;
    int p = rest & 1, rt = (rest >> 1) & 1, kk = (rest >> 2) & 7, kq2 = rest >> 5;
    int row = rt * 16 + (ln & 15);
    int grow = (row >> 3) * HID + nb * 8 + (row & 7);
    int k = kq2 * 256 + kk * 32 + (ln >> 4) * 8;
    const _Float16* src = (p ? whh_lo : whh_hi) + (size_t)grow * HID + k;
    *(half8*)(Wf + (size_t)s * 8) = *(const half8*)src;
  }

  // epilogue constants (tid<512): thread = (batch bo, cell j)
  int bo = tid >> 3, j = tid & 7;
  int within = bo & 15, btE = bo >> 4;
  float bh_[4], creg = 0.0f, uv[4] = {};
  if (tid < 512) {
#pragma unroll
    for (int q = 0; q < 4; q++) bh_[q] = bhh[q * HID + nb * 8 + j];
    creg = cout[(size_t)bo * HID + nb * 8 + j];
#pragma unroll
    for (int q = 0; q < 4; q++)
      uv[q] = u[(size_t)bo * GG + q * HID + nb * 8 + j];  // tt=0 prefetch
  }
  // h fragment byte offset for this lane's GEMM A-row
  u64 hOffB = (u64)(((bt * 16 + l15) * HID + kq * 256 + lg * 8) * 2);
  u64 hAhiB = (u64)(uintptr_t)hA_hi + hOffB;
  u64 hAloB = (u64)(uintptr_t)hA_lo + hOffB;
  u64 hBhiB = (u64)(uintptr_t)hB_hi + hOffB;
  u64 hBloB = (u64)(uintptr_t)hB_lo + hOffB;
  // h store mapping (tid<256): plane sp, row sb, 8B segment ss
  int sp = tid >> 7, sb = (tid & 127) >> 1, ss = tid & 1;
  u64* stA = (u64*)((sp ? hA_lo : hA_hi) + (size_t)sb * HID + nb * 8) + ss;
  u64* stB = (u64*)((sp ? hB_lo : hB_hi) + (size_t)sb * HID + nb * 8) + ss;
  __syncthreads();

  for (int tt = 0; tt < T; ++tt) {
    int gt = t0 + tt;
    u64 rhiB = (gt & 1) ? hBhiB : hAhiB;
    u64 rloB = (gt & 1) ? hBloB : hAloB;

    // ---- batched coherent h loads: 8 hi + 8 lo dwordx4, two asm blocks ----
    u32x4 H0, H1, H2, H3, H4, H5, H6, H7;
    u32x4 L0, L1, L2, L3, L4, L5, L6, L7;
    GLD8(H0, H1, H2, H3, H4, H5, H6, H7, rhiB);
    GLD8(L0, L1, L2, L3, L4, L5, L6, L7, rloB);
    asm volatile("s_waitcnt vmcnt(8)" ::: "memory");   // hi plane landed
    __builtin_amdgcn_sched_barrier(0);

    f32x4 aM0 = {}, aL0 = {}, aM1 = {}, aL1 = {};
    // phase 1: hi-plane MFMAs (4 per kk)
    {
      u32x4 hh[8] = {H0, H1, H2, H3, H4, H5, H6, H7};
#pragma unroll
      for (int kk = 0; kk < 8; ++kk) {
        half8 ah = __builtin_bit_cast(half8, hh[kk]);
        const _Float16* wb = Wf + (size_t)((kq * 8 + kk) * 4) * 512 + lane * 8;
        aM0 = mfma16(ah, *(const half8*)(wb), aM0);
        aL0 = mfma16(ah, *(const half8*)(wb + 512), aL0);
        aM1 = mfma16(ah, *(const half8*)(wb + 1024), aM1);
        aL1 = mfma16(ah, *(const half8*)(wb + 1536), aL1);
      }
    }
    asm volatile("s_waitcnt vmcnt(0)" ::: "memory");   // lo plane landed
    __builtin_amdgcn_sched_barrier(0);
    // phase 2: lo-plane MFMAs (2 per kk)
    {
      u32x4 ll[8] = {L0, L1, L2, L3, L4, L5, L6, L7};
#pragma unroll
      for (int kk = 0; kk < 8; ++kk) {
        half8 al = __builtin_bit_cast(half8, ll[kk]);
        const _Float16* wb = Wf + (size_t)((kq * 8 + kk) * 4) * 512 + lane * 8;
        aL0 = mfma16(al, *(const half8*)(wb), aL0);
        aL1 = mfma16(al, *(const half8*)(wb + 1024), aL1);
      }
    }
    f32x4 r0, r1;
#pragma unroll
    for (int i2 = 0; i2 < 4; ++i2) {
      r0[i2] = aM0[i2] + aL0[i2] * ISCL;
      r1[i2] = aM1[i2] + aL1[i2] * ISCL;
    }

    // ---- pairwise kq reduce in LDS, granule-rotation swizzled ----
    int kqh = kq >> 1;
    int p = (lg + l15) & 3;  // rotated granule slot
    int s0 = ((bt * 2 + kqh) * 2 + 0) * 256 + l15 * 16 + p * 4;
    int s1 = ((bt * 2 + kqh) * 2 + 1) * 256 + l15 * 16 + p * 4;
    if (kq & 1) {
      *(f32x4*)(red + s0) = r0;
      *(f32x4*)(red + s1) = r1;
    }
    __syncthreads();
    if (!(kq & 1)) {
      *(f32x4*)(red + s0) = r0 + *(const f32x4*)(red + s0);
      *(f32x4*)(red + s1) = r1 + *(const f32x4*)(red + s1);
    }
    // prefetch next step's u (overlaps)
    float uvN[4] = {};
    if (tid < 512 && tt + 1 < T) {
#pragma unroll
      for (int q = 0; q < 4; q++)
        uvN[q] = u[((size_t)(tt + 1) * BB + bo) * GG + q * HID + nb * 8 + j];
    }
    __syncthreads();

    if (tid < 512) {
      float gate[4];
#pragma unroll
      for (int q = 0; q < 4; q++) {
        int row = q * 8 + j, rt = row >> 4, col = row & 15;
        int wsl = (((within >> 2) + col) & 3) * 4 + (within & 3);  // de-swizzle
        float rec = red[((btE * 2 + 0) * 2 + rt) * 256 + col * 16 + wsl] +
                    red[((btE * 2 + 1) * 2 + rt) * 256 + col * 16 + wsl];
        gate[q] = uv[q] + rec + bh_[q];
      }
      float ig = 1.0f / (1.0f + expf(-gate[0]));
      float fg = 1.0f / (1.0f + expf(-gate[1]));
      float gg = tanhf(gate[2]);
      float og = 1.0f / (1.0f + expf(-gate[3]));
      creg = creg * fg + ig * gg;
      float hh = og * tanhf(creg);

      lout[((size_t)bo * SEQL + gt) * HID + nb * 8 + j] = hh;
      _Float16 shi, slo;
      fsplit(hh, shi, slo);
      hpk[bo * 8 + j] = __builtin_bit_cast(u16, shi);
      hpk[512 + bo * 8 + j] = __builtin_bit_cast(u16, slo);
      if (gt == SEQL - 1) hout[(size_t)bo * HID + nb * 8 + j] = hh;
      if (tt == T - 1)    cout[(size_t)bo * HID + nb * 8 + j] = creg;
#pragma unroll
      for (int q = 0; q < 4; q++) uv[q] = uvN[q];
    }
    __syncthreads();  // h pack complete

    // ---- coherent h stores: 256 x u64 from packed LDS (proven path) ----
    if (tid < 256) {
      u64 val = *(const u64*)(hpk + sp * 512 + sb * 8 + ss * 4);
      coh_store64((gt & 1) ? stA : stB, val);
    }

    if (tt + 1 < T) {
      asm volatile("s_waitcnt vmcnt(0)" ::: "memory");  // drain own stores
      __syncthreads();
      u32 target = (u32)(t0 + tt + 1);
      if (tid == 0) coh_store32(flags + nb * 32, target);
      if (wave == 0) {
        const u32* f0 = flags + (2 * lane) * 32;
        const u32* f1 = flags + (2 * lane + 1) * 32;
        while (!__all(coh_load32(f0) >= target && coh_load32(f1) >= target))
          __builtin_amdgcn_s_sleep(1);
      }
      __syncthreads();
    }
  }
}

extern "C" void kernel_launch(void* const* d_in, const int* in_sizes, int n_in,
                              void* d_out, int out_size, void* d_ws, size_t ws_size,
                              hipStream_t stream) {
  const float* x   = (const float*)d_in[0];
  const float* wih = (const float*)d_in[1];
  const float* whh = (const float*)d_in[2];
  const float* bih = (const float*)d_in[3];
  const float* bhh = (const float*)d_in[4];
  const float* h0  = (const float*)d_in[5];
  const float* c0  = (const float*)d_in[6];
  const float* v0  = (const float*)d_in[7];
  const float* m0  = (const float*)d_in[8];

  float* out  = (float*)d_out;
  float* lout = out;
  float* hout = out + (size_t)BB * SEQL * HID;
  float* cout = hout + (size_t)BB * HID;   // running c
  float* vout = cout + (size_t)BB * HID;   // running v
  float* mout = vout + (size_t)BB * GG;    // running m

  char* ws = (char*)d_ws;
  size_t o = 0;
  _Float16* wih_hi = (_Float16*)(ws + o); o += (size_t)GG * INF * 2;
  _Float16* wih_lo = (_Float16*)(ws + o); o += (size_t)GG * INF * 2;
  _Float16* whh_hi = (_Float16*)(ws + o); o += (size_t)GG * HID * 2;
  _Float16* whh_lo = (_Float16*)(ws + o); o += (size_t)GG * HID * 2;
  _Float16* hA_hi  = (_Float16*)(ws + o); o += (size_t)BB * HID * 2;
  _Float16* hA_lo  = (_Float16*)(ws + o); o += (size_t)BB * HID * 2;
  _Float16* hB_hi  = (_Float16*)(ws + o); o += (size_t)BB * HID * 2;
  _Float16* hB_lo  = (_Float16*)(ws + o); o += (size_t)BB * HID * 2;
  o = (o + 255) & ~(size_t)255;
  u32* flags = (u32*)(ws + o); o += (size_t)NWG * 32 * 4;
  float* U = (float*)(ws + o);

  const size_t STEP_BYTES = (size_t)BB * GG * sizeof(float);
  size_t cap = (ws_size > o) ? (ws_size - o) / STEP_BYTES : 1;
  if (cap < 1) cap = 1;
  int Tc = (int)(cap < (size_t)SEQL ? cap : (size_t)SEQL);

  transpose_split<<<dim3(GG / 32, INF / 32), 256, 0, stream>>>(wih, wih_hi, wih_lo, INF, GG);
  transpose_split<<<dim3(GG / 32, HID / 32), 256, 0, stream>>>(whh, whh_hi, whh_lo, HID, GG);
  init_state<<<(BB * GG) / 256, 256, 0, stream>>>(h0, c0, v0, m0, cout, vout, mout, hA_hi, hA_lo);
  hipMemsetAsync(flags, 0, (size_t)NWG * 32 * 4, stream);

  for (int t0 = 0; t0 < SEQL; t0 += Tc) {
    int T = (SEQL - t0 < Tc) ? (SEQL - t0) : Tc;
    grad_gemm<<<dim3(T, GG / 128), 256, 0, stream>>>(x, wih_hi, wih_lo, bih, U, t0);
    scan_vm<<<(BB * GG) / 256, 256, 0, stream>>>(U, vout, mout, T);
    rnn_persist<<<NWG, NTHR, SMEM_BYTES, stream>>>(
        U, whh_hi, whh_lo, bhh,
        hA_hi, hA_lo, hB_hi, hB_lo,
        lout, hout, cout, flags, t0, T);
  }
}

// Round 9
// 8525.190 us; speedup vs baseline: 4.5266x; 1.3402x over previous
//
#include <hip/hip_runtime.h>
#include <cstdint>
#include <cstddef>

#define BB   64
#define SEQL 512
#define INF  512
#define HID  1024
#define GG   4096   // 4*HID

#define MU_    0.9f
#define SSTEP_ 0.1f
#define BETA_  0.999f
#define EPS_   1e-16f
#define SCL    2048.0f
#define ISCL   (1.0f / 2048.0f)

#define NWG   128
#define NTHR  1024
#define WLDS  131072                     // weights, frag order
#define RLDS  16384                      // reduce slots
#define HPKB  2048                       // h pack buffer (2 planes x 512 halves)
#define SMEM_BYTES (WLDS + RLDS + HPKB)  // 149504 <= 160 KiB

typedef unsigned short u16;
typedef unsigned int   u32;
typedef unsigned long long u64;
typedef _Float16 half8 __attribute__((ext_vector_type(8)));
typedef float f32x4 __attribute__((ext_vector_type(4)));
typedef u32 u32x4 __attribute__((ext_vector_type(4)));

__device__ __forceinline__ f32x4 mfma16(half8 a, half8 b, f32x4 c) {
  return __builtin_amdgcn_mfma_f32_16x16x32_f16(a, b, c, 0, 0, 0);
}
__device__ __forceinline__ void fsplit(float v, _Float16& hi, _Float16& lo) {
  hi = (_Float16)v;
  lo = (_Float16)((v - (float)hi) * SCL);
}
// device-coherent (cross-XCD) atomic ops for control & h stores (proven path)
__device__ __forceinline__ u32 coh_load32(const u32* p) {
  return __hip_atomic_load(p, __ATOMIC_RELAXED, __HIP_MEMORY_SCOPE_AGENT);
}
__device__ __forceinline__ void coh_store32(u32* p, u32 v) {
  __hip_atomic_store(p, v, __ATOMIC_RELAXED, __HIP_MEMORY_SCOPE_AGENT);
}
__device__ __forceinline__ void coh_store64(u64* p, u64 v) {
  __hip_atomic_store(p, v, __ATOMIC_RELAXED, __HIP_MEMORY_SCOPE_AGENT);
}

// 8 batched device-coherent 16B loads from base addr (+ kk*64B), one asm block:
// un-sinkable, un-splittable. Values valid only after s_waitcnt vmcnt.
#define GLD8(o0,o1,o2,o3,o4,o5,o6,o7,addr)                      \
  asm volatile(                                                 \
    "global_load_dwordx4 %0, %8, off sc0 sc1\n\t"               \
    "global_load_dwordx4 %1, %8, off offset:64 sc0 sc1\n\t"     \
    "global_load_dwordx4 %2, %8, off offset:128 sc0 sc1\n\t"    \
    "global_load_dwordx4 %3, %8, off offset:192 sc0 sc1\n\t"    \
    "global_load_dwordx4 %4, %8, off offset:256 sc0 sc1\n\t"    \
    "global_load_dwordx4 %5, %8, off offset:320 sc0 sc1\n\t"    \
    "global_load_dwordx4 %6, %8, off offset:384 sc0 sc1\n\t"    \
    "global_load_dwordx4 %7, %8, off offset:448 sc0 sc1"        \
    : "=&v"(o0), "=&v"(o1), "=&v"(o2), "=&v"(o3),               \
      "=&v"(o4), "=&v"(o5), "=&v"(o6), "=&v"(o7)                \
    : "v"(addr))

// hi-plane MFMA cluster for one kk (consumes a named H tuple; no temp arrays)
#define HIMF(Hk, kk)                                                        \
  {                                                                         \
    half8 ah = __builtin_bit_cast(half8, Hk);                               \
    const _Float16* wb = Wf + (size_t)((kq * 8 + (kk)) * 4) * 512 + lane * 8;\
    aM0 = mfma16(ah, *(const half8*)(wb), aM0);                             \
    aL0 = mfma16(ah, *(const half8*)(wb + 512), aL0);                       \
    aM1 = mfma16(ah, *(const half8*)(wb + 1024), aM1);                      \
    aL1 = mfma16(ah, *(const half8*)(wb + 1536), aL1);                      \
  }
// lo-plane MFMA cluster for one kk
#define LOMF(Lk, kk)                                                        \
  {                                                                         \
    half8 al = __builtin_bit_cast(half8, Lk);                               \
    const _Float16* wb = Wf + (size_t)((kq * 8 + (kk)) * 4) * 512 + lane * 8;\
    aL0 = mfma16(al, *(const half8*)(wb), aL0);                             \
    aL1 = mfma16(al, *(const half8*)(wb + 1024), aL1);                      \
  }

// ---- transpose + f16-split: src [R][C] f32 -> dhi/dlo [C][R] f16 ----
__global__ __launch_bounds__(256) void transpose_split(const float* __restrict__ src,
                                                       _Float16* __restrict__ dhi,
                                                       _Float16* __restrict__ dlo,
                                                       int R, int C) {
  __shared__ float tile[32][33];
  int c0 = blockIdx.x * 32, r0 = blockIdx.y * 32;
  int tx = threadIdx.x & 31, ty = threadIdx.x >> 5;
#pragma unroll
  for (int i = 0; i < 32; i += 8)
    tile[ty + i][tx] = src[(size_t)(r0 + ty + i) * C + (c0 + tx)];
  __syncthreads();
#pragma unroll
  for (int i = 0; i < 32; i += 8) {
    float v = tile[tx][ty + i];
    _Float16 hi, lo;
    fsplit(v, hi, lo);
    size_t o = (size_t)(c0 + ty + i) * R + (r0 + tx);
    dhi[o] = hi;
    dlo[o] = lo;
  }
}

// ---- init running state ----
__global__ __launch_bounds__(256) void init_state(const float* __restrict__ h0,
                                                  const float* __restrict__ c0,
                                                  const float* __restrict__ v0,
                                                  const float* __restrict__ m0,
                                                  float* __restrict__ co,
                                                  float* __restrict__ vo,
                                                  float* __restrict__ mo,
                                                  _Float16* __restrict__ hhi,
                                                  _Float16* __restrict__ hlo) {
  int i = blockIdx.x * 256 + threadIdx.x;
  if (i < BB * GG) { vo[i] = v0[i]; mo[i] = m0[i]; }
  if (i < BB * HID) {
    co[i] = c0[i];
    _Float16 hi, lo;
    fsplit(h0[i], hi, lo);
    hhi[i] = hi;
    hlo[i] = lo;
  }
}

// ---- grad chunk GEMM (f16-split), 128-col tiles ----
__global__ __launch_bounds__(256) void grad_gemm(const float* __restrict__ x,
                                                 const _Float16* __restrict__ whi,
                                                 const _Float16* __restrict__ wlo,
                                                 const float* __restrict__ bih,
                                                 float* __restrict__ grad,  // [Tc][B][G]
                                                 int t0) {
  int tloc = blockIdx.x;
  int n0 = blockIdx.y * 128;
  int wave = threadIdx.x >> 6, lane = threadIdx.x & 63;
  int l15 = lane & 15, lg = lane >> 4;
  int t = t0 + tloc;
  int b = 16 * wave + l15;
  const float* xa = x + (size_t)b * (SEQL * INF) + (size_t)t * INF + lg * 8;
  const _Float16* wh = whi + (size_t)(n0 + l15) * INF + lg * 8;
  const _Float16* wl = wlo + (size_t)(n0 + l15) * INF + lg * 8;

  f32x4 accM[8] = {};
  f32x4 accL[8] = {};
  for (int kk = 0; kk < INF; kk += 32) {
    f32x4 x0 = *(const f32x4*)(xa + kk);
    f32x4 x1 = *(const f32x4*)(xa + kk + 4);
    half8 ah, al;
#pragma unroll
    for (int j = 0; j < 4; j++) {
      _Float16 hi, lo;
      fsplit(x0[j], hi, lo); ah[j] = hi; al[j] = lo;
      fsplit(x1[j], hi, lo); ah[4 + j] = hi; al[4 + j] = lo;
    }
#pragma unroll
    for (int nt = 0; nt < 8; nt++) {
      half8 bh = *(const half8*)(wh + (size_t)nt * 16 * INF + kk);
      half8 bl = *(const half8*)(wl + (size_t)nt * 16 * INF + kk);
      accM[nt] = mfma16(ah, bh, accM[nt]);
      accL[nt] = mfma16(al, bh, accL[nt]);
      accL[nt] = mfma16(ah, bl, accL[nt]);
    }
  }
#pragma unroll
  for (int nt = 0; nt < 8; nt++) {
    int g = n0 + nt * 16 + l15;
    float bias = bih[g];
#pragma unroll
    for (int r = 0; r < 4; r++) {
      int bo = 16 * wave + lg * 4 + r;
      grad[((size_t)tloc * BB + bo) * GG + g] = accM[nt][r] + accL[nt][r] * ISCL + bias;
    }
  }
}

// ---- momentum/second-moment scan: grad -> u = v'/(sqrt(m')+eps), in place ----
__global__ __launch_bounds__(256) void scan_vm(float* __restrict__ grad,
                                               float* __restrict__ vst,
                                               float* __restrict__ mst,
                                               int T) {
  int i = blockIdx.x * 256 + threadIdx.x;
  float v = vst[i], m = mst[i];
  for (int tt = 0; tt < T; ++tt) {
    size_t o = (size_t)tt * (BB * GG) + i;
    float g = grad[o];
    v = MU_ * v + SSTEP_ * g;
    m = BETA_ * m + (1.0f - BETA_) * g * g;
    grad[o] = v / (sqrtf(m) + EPS_);
  }
  vst[i] = v;
  mst[i] = m;
}

// ---- persistent recurrent kernel ----
// 128 wgs x 1024 thr (16 waves). wg nb owns cells nb*8..+7 (32 G-rows).
// W_hh split in LDS (frag order). wave w: bt=w>>2 (16 batch rows), kq=w&3.
// h exchange: asm-batched coherent dwordx4 loads (2 phases), LDS-packed
// coherent u64 stores. Barrier: per-wg padded flags + read-only poll.
// waves_per_eu(4,4): LDS is dynamic (invisible to occupancy heuristic) but
// 146KiB LDS pins 1 wg/CU = 4 waves/EU -> allow up to 512 VGPRs (kills the
// round-8 spill where heuristic chose 64 VGPRs and spilled the H/L tuples).
__global__ __attribute__((amdgpu_flat_work_group_size(NTHR, NTHR),
                          amdgpu_waves_per_eu(4, 4))) void rnn_persist(
    const float* __restrict__ u,          // [T][B][G]
    const _Float16* __restrict__ whh_hi, const _Float16* __restrict__ whh_lo,
    const float* __restrict__ bhh,
    _Float16* __restrict__ hA_hi, _Float16* __restrict__ hA_lo,
    _Float16* __restrict__ hB_hi, _Float16* __restrict__ hB_lo,
    float* __restrict__ lout, float* __restrict__ hout,
    float* __restrict__ cout, u32* __restrict__ flags, int t0, int T) {
  extern __shared__ char smem[];
  _Float16* Wf = (_Float16*)smem;                 // 128 KiB frag-order weights
  float* red = (float*)(smem + WLDS);             // reduce: [bt4][kqh2][rt2][16][16]
  u16* hpk = (u16*)(smem + WLDS + RLDS);          // [2][512] packed h halves

  int tid = threadIdx.x;
  int wave = tid >> 6, lane = tid & 63;
  int l15 = lane & 15, lg = lane >> 4;
  int bt = wave >> 2, kq = wave & 3;
  int nb = blockIdx.x;

  // ---- stage W_hh slice into LDS in fragment order ----
  for (int s = tid; s < 8192; s += NTHR) {
    int ln = s & 63, rest = s >> 6;
    int p = rest & 1, rt = (rest >> 1) & 1, kk = (rest >> 2) & 7, kq2 = rest >> 5;
    int row = rt * 16 + (ln & 15);
    int grow = (row >> 3) * HID + nb * 8 + (row & 7);
    int k = kq2 * 256 + kk * 32 + (ln >> 4) * 8;
    const _Float16* src = (p ? whh_lo : whh_hi) + (size_t)grow * HID + k;
    *(half8*)(Wf + (size_t)s * 8) = *(const half8*)src;
  }

  // epilogue constants (tid<512): thread = (batch bo, cell j)
  int bo = tid >> 3, j = tid & 7;
  int within = bo & 15, btE = bo >> 4;
  float bh_[4], creg = 0.0f, uv[4] = {};
  if (tid < 512) {
#pragma unroll
    for (int q = 0; q < 4; q++) bh_[q] = bhh[q * HID + nb * 8 + j];
    creg = cout[(size_t)bo * HID + nb * 8 + j];
#pragma unroll
    for (int q = 0; q < 4; q++)
      uv[q] = u[(size_t)bo * GG + q * HID + nb * 8 + j];  // tt=0 prefetch
  }
  // h fragment byte offset for this lane's GEMM A-row
  u64 hOffB = (u64)(((bt * 16 + l15) * HID + kq * 256 + lg * 8) * 2);
  u64 hAhiB = (u64)(uintptr_t)hA_hi + hOffB;
  u64 hAloB = (u64)(uintptr_t)hA_lo + hOffB;
  u64 hBhiB = (u64)(uintptr_t)hB_hi + hOffB;
  u64 hBloB = (u64)(uintptr_t)hB_lo + hOffB;
  // h store mapping (tid<256): plane sp, row sb, 8B segment ss
  int sp = tid >> 7, sb = (tid & 127) >> 1, ss = tid & 1;
  u64* stA = (u64*)((sp ? hA_lo : hA_hi) + (size_t)sb * HID + nb * 8) + ss;
  u64* stB = (u64*)((sp ? hB_lo : hB_hi) + (size_t)sb * HID + nb * 8) + ss;
  __syncthreads();

  for (int tt = 0; tt < T; ++tt) {
    int gt = t0 + tt;
    u64 rhiB = (gt & 1) ? hBhiB : hAhiB;
    u64 rloB = (gt & 1) ? hBloB : hAloB;

    // ---- batched coherent h loads: 8 hi + 8 lo dwordx4, two asm blocks ----
    u32x4 H0, H1, H2, H3, H4, H5, H6, H7;
    u32x4 L0, L1, L2, L3, L4, L5, L6, L7;
    GLD8(H0, H1, H2, H3, H4, H5, H6, H7, rhiB);
    GLD8(L0, L1, L2, L3, L4, L5, L6, L7, rloB);
    asm volatile("s_waitcnt vmcnt(8)" ::: "memory");   // hi plane landed
    __builtin_amdgcn_sched_barrier(0);

    f32x4 aM0 = {}, aL0 = {}, aM1 = {}, aL1 = {};
    // phase 1: hi-plane MFMAs (4 per kk), named tuples, no temp arrays
    HIMF(H0, 0) HIMF(H1, 1) HIMF(H2, 2) HIMF(H3, 3)
    HIMF(H4, 4) HIMF(H5, 5) HIMF(H6, 6) HIMF(H7, 7)
    asm volatile("s_waitcnt vmcnt(0)" ::: "memory");   // lo plane landed
    __builtin_amdgcn_sched_barrier(0);
    // phase 2: lo-plane MFMAs (2 per kk)
    LOMF(L0, 0) LOMF(L1, 1) LOMF(L2, 2) LOMF(L3, 3)
    LOMF(L4, 4) LOMF(L5, 5) LOMF(L6, 6) LOMF(L7, 7)

    f32x4 r0, r1;
#pragma unroll
    for (int i2 = 0; i2 < 4; ++i2) {
      r0[i2] = aM0[i2] + aL0[i2] * ISCL;
      r1[i2] = aM1[i2] + aL1[i2] * ISCL;
    }

    // ---- pairwise kq reduce in LDS, granule-rotation swizzled ----
    int kqh = kq >> 1;
    int p = (lg + l15) & 3;  // rotated granule slot
    int s0 = ((bt * 2 + kqh) * 2 + 0) * 256 + l15 * 16 + p * 4;
    int s1 = ((bt * 2 + kqh) * 2 + 1) * 256 + l15 * 16 + p * 4;
    if (kq & 1) {
      *(f32x4*)(red + s0) = r0;
      *(f32x4*)(red + s1) = r1;
    }
    __syncthreads();
    if (!(kq & 1)) {
      *(f32x4*)(red + s0) = r0 + *(const f32x4*)(red + s0);
      *(f32x4*)(red + s1) = r1 + *(const f32x4*)(red + s1);
    }
    // prefetch next step's u (overlaps)
    float uvN[4] = {};
    if (tid < 512 && tt + 1 < T) {
#pragma unroll
      for (int q = 0; q < 4; q++)
        uvN[q] = u[((size_t)(tt + 1) * BB + bo) * GG + q * HID + nb * 8 + j];
    }
    __syncthreads();

    if (tid < 512) {
      float gate[4];
#pragma unroll
      for (int q = 0; q < 4; q++) {
        int row = q * 8 + j, rt = row >> 4, col = row & 15;
        int wsl = (((within >> 2) + col) & 3) * 4 + (within & 3);  // de-swizzle
        float rec = red[((btE * 2 + 0) * 2 + rt) * 256 + col * 16 + wsl] +
                    red[((btE * 2 + 1) * 2 + rt) * 256 + col * 16 + wsl];
        gate[q] = uv[q] + rec + bh_[q];
      }
      float ig = 1.0f / (1.0f + expf(-gate[0]));
      float fg = 1.0f / (1.0f + expf(-gate[1]));
      float gg = tanhf(gate[2]);
      float og = 1.0f / (1.0f + expf(-gate[3]));
      creg = creg * fg + ig * gg;
      float hh = og * tanhf(creg);

      lout[((size_t)bo * SEQL + gt) * HID + nb * 8 + j] = hh;
      _Float16 shi, slo;
      fsplit(hh, shi, slo);
      hpk[bo * 8 + j] = __builtin_bit_cast(u16, shi);
      hpk[512 + bo * 8 + j] = __builtin_bit_cast(u16, slo);
      if (gt == SEQL - 1) hout[(size_t)bo * HID + nb * 8 + j] = hh;
      if (tt == T - 1)    cout[(size_t)bo * HID + nb * 8 + j] = creg;
#pragma unroll
      for (int q = 0; q < 4; q++) uv[q] = uvN[q];
    }
    __syncthreads();  // h pack complete

    // ---- coherent h stores: 256 x u64 from packed LDS (proven path) ----
    if (tid < 256) {
      u64 val = *(const u64*)(hpk + sp * 512 + sb * 8 + ss * 4);
      coh_store64((gt & 1) ? stA : stB, val);
    }

    if (tt + 1 < T) {
      asm volatile("s_waitcnt vmcnt(0)" ::: "memory");  // drain own stores
      __syncthreads();
      u32 target = (u32)(t0 + tt + 1);
      if (tid == 0) coh_store32(flags + nb * 32, target);
      if (wave == 0) {
        const u32* f0 = flags + (2 * lane) * 32;
        const u32* f1 = flags + (2 * lane + 1) * 32;
        while (!__all(coh_load32(f0) >= target && coh_load32(f1) >= target))
          __builtin_amdgcn_s_sleep(1);
      }
      __syncthreads();
    }
  }
}

extern "C" void kernel_launch(void* const* d_in, const int* in_sizes, int n_in,
                              void* d_out, int out_size, void* d_ws, size_t ws_size,
                              hipStream_t stream) {
  const float* x   = (const float*)d_in[0];
  const float* wih = (const float*)d_in[1];
  const float* whh = (const float*)d_in[2];
  const float* bih = (const float*)d_in[3];
  const float* bhh = (const float*)d_in[4];
  const float* h0  = (const float*)d_in[5];
  const float* c0  = (const float*)d_in[6];
  const float* v0  = (const float*)d_in[7];
  const float* m0  = (const float*)d_in[8];

  float* out  = (float*)d_out;
  float* lout = out;
  float* hout = out + (size_t)BB * SEQL * HID;
  float* cout = hout + (size_t)BB * HID;   // running c
  float* vout = cout + (size_t)BB * HID;   // running v
  float* mout = vout + (size_t)BB * GG;    // running m

  char* ws = (char*)d_ws;
  size_t o = 0;
  _Float16* wih_hi = (_Float16*)(ws + o); o += (size_t)GG * INF * 2;
  _Float16* wih_lo = (_Float16*)(ws + o); o += (size_t)GG * INF * 2;
  _Float16* whh_hi = (_Float16*)(ws + o); o += (size_t)GG * HID * 2;
  _Float16* whh_lo = (_Float16*)(ws + o); o += (size_t)GG * HID * 2;
  _Float16* hA_hi  = (_Float16*)(ws + o); o += (size_t)BB * HID * 2;
  _Float16* hA_lo  = (_Float16*)(ws + o); o += (size_t)BB * HID * 2;
  _Float16* hB_hi  = (_Float16*)(ws + o); o += (size_t)BB * HID * 2;
  _Float16* hB_lo  = (_Float16*)(ws + o); o += (size_t)BB * HID * 2;
  o = (o + 255) & ~(size_t)255;
  u32* flags = (u32*)(ws + o); o += (size_t)NWG * 32 * 4;
  float* U = (float*)(ws + o);

  const size_t STEP_BYTES = (size_t)BB * GG * sizeof(float);
  size_t cap = (ws_size > o) ? (ws_size - o) / STEP_BYTES : 1;
  if (cap < 1) cap = 1;
  int Tc = (int)(cap < (size_t)SEQL ? cap : (size_t)SEQL);

  transpose_split<<<dim3(GG / 32, INF / 32), 256, 0, stream>>>(wih, wih_hi, wih_lo, INF, GG);
  transpose_split<<<dim3(GG / 32, HID / 32), 256, 0, stream>>>(whh, whh_hi, whh_lo, HID, GG);
  init_state<<<(BB * GG) / 256, 256, 0, stream>>>(h0, c0, v0, m0, cout, vout, mout, hA_hi, hA_lo);
  hipMemsetAsync(flags, 0, (size_t)NWG * 32 * 4, stream);

  for (int t0 = 0; t0 < SEQL; t0 += Tc) {
    int T = (SEQL - t0 < Tc) ? (SEQL - t0) : Tc;
    grad_gemm<<<dim3(T, GG / 128), 256, 0, stream>>>(x, wih_hi, wih_lo, bih, U, t0);
    scan_vm<<<(BB * GG) / 256, 256, 0, stream>>>(U, vout, mout, T);
    rnn_persist<<<NWG, NTHR, SMEM_BYTES, stream>>>(
        U, whh_hi, whh_lo, bhh,
        hA_hi, hA_lo, hB_hi, hB_lo,
        lout, hout, cout, flags, t0, T);
  }
}

// Round 10
// 6587.614 us; speedup vs baseline: 5.8579x; 1.2941x over previous
//
#include <hip/hip_runtime.h>
#include <cstdint>
#include <cstddef>

#define BB   64
#define SEQL 512
#define INF  512
#define HID  1024
#define GG   4096   // 4*HID

#define MU_    0.9f
#define SSTEP_ 0.1f
#define BETA_  0.999f
#define EPS_   1e-16f
#define SCL    2048.0f
#define ISCL   (1.0f / 2048.0f)

#define NWG   128
#define NTHR  1024
#define WLDS  131072                     // weights, frag order (W split: hi+lo)
#define RLDS  16384                      // reduce slots
#define HPKB  1024                       // h pack buffer (512 halves, single plane)
#define SMEM_BYTES (WLDS + RLDS + HPKB)  // 148480 <= 160 KiB

typedef unsigned short u16;
typedef unsigned int   u32;
typedef unsigned long long u64;
typedef _Float16 half8 __attribute__((ext_vector_type(8)));
typedef float f32x4 __attribute__((ext_vector_type(4)));
typedef u32 u32x4 __attribute__((ext_vector_type(4)));

__device__ __forceinline__ f32x4 mfma16(half8 a, half8 b, f32x4 c) {
  return __builtin_amdgcn_mfma_f32_16x16x32_f16(a, b, c, 0, 0, 0);
}
__device__ __forceinline__ void fsplit(float v, _Float16& hi, _Float16& lo) {
  hi = (_Float16)v;
  lo = (_Float16)((v - (float)hi) * SCL);
}
// device-coherent (cross-XCD) atomic ops for control & h stores (proven path)
__device__ __forceinline__ u32 coh_load32(const u32* p) {
  return __hip_atomic_load(p, __ATOMIC_RELAXED, __HIP_MEMORY_SCOPE_AGENT);
}
__device__ __forceinline__ void coh_store32(u32* p, u32 v) {
  __hip_atomic_store(p, v, __ATOMIC_RELAXED, __HIP_MEMORY_SCOPE_AGENT);
}
__device__ __forceinline__ void coh_store64(u64* p, u64 v) {
  __hip_atomic_store(p, v, __ATOMIC_RELAXED, __HIP_MEMORY_SCOPE_AGENT);
}

// 8 batched device-coherent 16B loads from base addr (+ kk*64B), one asm block:
// un-sinkable, un-splittable. Values valid only after s_waitcnt vmcnt.
#define GLD8(o0,o1,o2,o3,o4,o5,o6,o7,addr)                      \
  asm volatile(                                                 \
    "global_load_dwordx4 %0, %8, off sc0 sc1\n\t"               \
    "global_load_dwordx4 %1, %8, off offset:64 sc0 sc1\n\t"     \
    "global_load_dwordx4 %2, %8, off offset:128 sc0 sc1\n\t"    \
    "global_load_dwordx4 %3, %8, off offset:192 sc0 sc1\n\t"    \
    "global_load_dwordx4 %4, %8, off offset:256 sc0 sc1\n\t"    \
    "global_load_dwordx4 %5, %8, off offset:320 sc0 sc1\n\t"    \
    "global_load_dwordx4 %6, %8, off offset:384 sc0 sc1\n\t"    \
    "global_load_dwordx4 %7, %8, off offset:448 sc0 sc1"        \
    : "=&v"(o0), "=&v"(o1), "=&v"(o2), "=&v"(o3),               \
      "=&v"(o4), "=&v"(o5), "=&v"(o6), "=&v"(o7)                \
    : "v"(addr))

// MFMA cluster for one kk: h_f16 fragment x {W_hi, W_lo} for both rt halves.
#define HIMF(Hk, kk)                                                        \
  {                                                                         \
    half8 ah = __builtin_bit_cast(half8, Hk);                               \
    const _Float16* wb = Wf + (size_t)((kq * 8 + (kk)) * 4) * 512 + lane * 8;\
    aM0 = mfma16(ah, *(const half8*)(wb), aM0);                             \
    aL0 = mfma16(ah, *(const half8*)(wb + 512), aL0);                       \
    aM1 = mfma16(ah, *(const half8*)(wb + 1024), aM1);                      \
    aL1 = mfma16(ah, *(const half8*)(wb + 1536), aL1);                      \
  }

// ---- transpose + f16-split: src [R][C] f32 -> dhi/dlo [C][R] f16 ----
__global__ __launch_bounds__(256) void transpose_split(const float* __restrict__ src,
                                                       _Float16* __restrict__ dhi,
                                                       _Float16* __restrict__ dlo,
                                                       int R, int C) {
  __shared__ float tile[32][33];
  int c0 = blockIdx.x * 32, r0 = blockIdx.y * 32;
  int tx = threadIdx.x & 31, ty = threadIdx.x >> 5;
#pragma unroll
  for (int i = 0; i < 32; i += 8)
    tile[ty + i][tx] = src[(size_t)(r0 + ty + i) * C + (c0 + tx)];
  __syncthreads();
#pragma unroll
  for (int i = 0; i < 32; i += 8) {
    float v = tile[tx][ty + i];
    _Float16 hi, lo;
    fsplit(v, hi, lo);
    size_t o = (size_t)(c0 + ty + i) * R + (r0 + tx);
    dhi[o] = hi;
    dlo[o] = lo;
  }
}

// ---- init running state (h -> single f16 plane) ----
__global__ __launch_bounds__(256) void init_state(const float* __restrict__ h0,
                                                  const float* __restrict__ c0,
                                                  const float* __restrict__ v0,
                                                  const float* __restrict__ m0,
                                                  float* __restrict__ co,
                                                  float* __restrict__ vo,
                                                  float* __restrict__ mo,
                                                  _Float16* __restrict__ hhi) {
  int i = blockIdx.x * 256 + threadIdx.x;
  if (i < BB * GG) { vo[i] = v0[i]; mo[i] = m0[i]; }
  if (i < BB * HID) {
    co[i] = c0[i];
    hhi[i] = (_Float16)h0[i];
  }
}

// ---- grad chunk GEMM (f16-split), 128-col tiles ----
__global__ __launch_bounds__(256) void grad_gemm(const float* __restrict__ x,
                                                 const _Float16* __restrict__ whi,
                                                 const _Float16* __restrict__ wlo,
                                                 const float* __restrict__ bih,
                                                 float* __restrict__ grad,  // [Tc][B][G]
                                                 int t0) {
  int tloc = blockIdx.x;
  int n0 = blockIdx.y * 128;
  int wave = threadIdx.x >> 6, lane = threadIdx.x & 63;
  int l15 = lane & 15, lg = lane >> 4;
  int t = t0 + tloc;
  int b = 16 * wave + l15;
  const float* xa = x + (size_t)b * (SEQL * INF) + (size_t)t * INF + lg * 8;
  const _Float16* wh = whi + (size_t)(n0 + l15) * INF + lg * 8;
  const _Float16* wl = wlo + (size_t)(n0 + l15) * INF + lg * 8;

  f32x4 accM[8] = {};
  f32x4 accL[8] = {};
  for (int kk = 0; kk < INF; kk += 32) {
    f32x4 x0 = *(const f32x4*)(xa + kk);
    f32x4 x1 = *(const f32x4*)(xa + kk + 4);
    half8 ah, al;
#pragma unroll
    for (int j = 0; j < 4; j++) {
      _Float16 hi, lo;
      fsplit(x0[j], hi, lo); ah[j] = hi; al[j] = lo;
      fsplit(x1[j], hi, lo); ah[4 + j] = hi; al[4 + j] = lo;
    }
#pragma unroll
    for (int nt = 0; nt < 8; nt++) {
      half8 bh = *(const half8*)(wh + (size_t)nt * 16 * INF + kk);
      half8 bl = *(const half8*)(wl + (size_t)nt * 16 * INF + kk);
      accM[nt] = mfma16(ah, bh, accM[nt]);
      accL[nt] = mfma16(al, bh, accL[nt]);
      accL[nt] = mfma16(ah, bl, accL[nt]);
    }
  }
#pragma unroll
  for (int nt = 0; nt < 8; nt++) {
    int g = n0 + nt * 16 + l15;
    float bias = bih[g];
#pragma unroll
    for (int r = 0; r < 4; r++) {
      int bo = 16 * wave + lg * 4 + r;
      grad[((size_t)tloc * BB + bo) * GG + g] = accM[nt][r] + accL[nt][r] * ISCL + bias;
    }
  }
}

// ---- momentum/second-moment scan: grad -> u = v'/(sqrt(m')+eps), in place ----
__global__ __launch_bounds__(256) void scan_vm(float* __restrict__ grad,
                                               float* __restrict__ vst,
                                               float* __restrict__ mst,
                                               int T) {
  int i = blockIdx.x * 256 + threadIdx.x;
  float v = vst[i], m = mst[i];
  for (int tt = 0; tt < T; ++tt) {
    size_t o = (size_t)tt * (BB * GG) + i;
    float g = grad[o];
    v = MU_ * v + SSTEP_ * g;
    m = BETA_ * m + (1.0f - BETA_) * g * g;
    grad[o] = v / (sqrtf(m) + EPS_);
  }
  vst[i] = v;
  mst[i] = m;
}

// ---- persistent recurrent kernel ----
// 128 wgs x 1024 thr (16 waves). wg nb owns cells nb*8..+7 (32 G-rows).
// W_hh SPLIT (hi+lo) in LDS (frag order) — full precision in W.
// h exchanged as SINGLE f16 plane (halves LLC broadcast: 16 MiB/step).
// wave w: bt=w>>2 (16 batch rows), kq=w&3. Barrier: per-wg padded flags +
// read-only poll. waves_per_eu(4,4) pins the VGPR budget (round-9 fix).
__global__ __attribute__((amdgpu_flat_work_group_size(NTHR, NTHR),
                          amdgpu_waves_per_eu(4, 4))) void rnn_persist(
    const float* __restrict__ u,          // [T][B][G]
    const _Float16* __restrict__ whh_hi, const _Float16* __restrict__ whh_lo,
    const float* __restrict__ bhh,
    _Float16* __restrict__ hA, _Float16* __restrict__ hB,
    float* __restrict__ lout, float* __restrict__ hout,
    float* __restrict__ cout, u32* __restrict__ flags, int t0, int T) {
  extern __shared__ char smem[];
  _Float16* Wf = (_Float16*)smem;                 // 128 KiB frag-order weights
  float* red = (float*)(smem + WLDS);             // reduce: [bt4][kqh2][rt2][16][16]
  u16* hpk = (u16*)(smem + WLDS + RLDS);          // [512] packed h halves

  int tid = threadIdx.x;
  int wave = tid >> 6, lane = tid & 63;
  int l15 = lane & 15, lg = lane >> 4;
  int bt = wave >> 2, kq = wave & 3;
  int nb = blockIdx.x;

  // ---- stage W_hh slice into LDS in fragment order ----
  for (int s = tid; s < 8192; s += NTHR) {
    int ln = s & 63, rest = s >> 6;
    int p = rest & 1, rt = (rest >> 1) & 1, kk = (rest >> 2) & 7, kq2 = rest >> 5;
    int row = rt * 16 + (ln & 15);
    int grow = (row >> 3) * HID + nb * 8 + (row & 7);
    int k = kq2 * 256 + kk * 32 + (ln >> 4) * 8;
    const _Float16* src = (p ? whh_lo : whh_hi) + (size_t)grow * HID + k;
    *(half8*)(Wf + (size_t)s * 8) = *(const half8*)src;
  }

  // epilogue constants (tid<512): thread = (batch bo, cell j)
  int bo = tid >> 3, j = tid & 7;
  int within = bo & 15, btE = bo >> 4;
  float bh_[4], creg = 0.0f, uv[4] = {};
  if (tid < 512) {
#pragma unroll
    for (int q = 0; q < 4; q++) bh_[q] = bhh[q * HID + nb * 8 + j];
    creg = cout[(size_t)bo * HID + nb * 8 + j];
#pragma unroll
    for (int q = 0; q < 4; q++)
      uv[q] = u[(size_t)bo * GG + q * HID + nb * 8 + j];  // tt=0 prefetch
  }
  // h fragment byte offset for this lane's GEMM A-row
  u64 hOffB = (u64)(((bt * 16 + l15) * HID + kq * 256 + lg * 8) * 2);
  u64 hAB = (u64)(uintptr_t)hA + hOffB;
  u64 hBB = (u64)(uintptr_t)hB + hOffB;
  // h store mapping (tid<128): row sb, 8B segment ss
  int sb = tid >> 1, ss = tid & 1;
  u64* stA = (u64*)(hA + (size_t)sb * HID + nb * 8) + ss;
  u64* stB = (u64*)(hB + (size_t)sb * HID + nb * 8) + ss;
  __syncthreads();

  for (int tt = 0; tt < T; ++tt) {
    int gt = t0 + tt;
    u64 rB = (gt & 1) ? hBB : hAB;

    // ---- batched coherent h loads: 8 dwordx4, one asm block ----
    u32x4 H0, H1, H2, H3, H4, H5, H6, H7;
    GLD8(H0, H1, H2, H3, H4, H5, H6, H7, rB);
    asm volatile("s_waitcnt vmcnt(0)" ::: "memory");   // h landed
    __builtin_amdgcn_sched_barrier(0);

    f32x4 aM0 = {}, aL0 = {}, aM1 = {}, aL1 = {};
    HIMF(H0, 0) HIMF(H1, 1) HIMF(H2, 2) HIMF(H3, 3)
    HIMF(H4, 4) HIMF(H5, 5) HIMF(H6, 6) HIMF(H7, 7)

    f32x4 r0, r1;
#pragma unroll
    for (int i2 = 0; i2 < 4; ++i2) {
      r0[i2] = aM0[i2] + aL0[i2] * ISCL;
      r1[i2] = aM1[i2] + aL1[i2] * ISCL;
    }

    // ---- pairwise kq reduce in LDS, granule-rotation swizzled ----
    int kqh = kq >> 1;
    int p = (lg + l15) & 3;  // rotated granule slot
    int s0 = ((bt * 2 + kqh) * 2 + 0) * 256 + l15 * 16 + p * 4;
    int s1 = ((bt * 2 + kqh) * 2 + 1) * 256 + l15 * 16 + p * 4;
    if (kq & 1) {
      *(f32x4*)(red + s0) = r0;
      *(f32x4*)(red + s1) = r1;
    }
    __syncthreads();
    if (!(kq & 1)) {
      *(f32x4*)(red + s0) = r0 + *(const f32x4*)(red + s0);
      *(f32x4*)(red + s1) = r1 + *(const f32x4*)(red + s1);
    }
    // prefetch next step's u (overlaps)
    float uvN[4] = {};
    if (tid < 512 && tt + 1 < T) {
#pragma unroll
      for (int q = 0; q < 4; q++)
        uvN[q] = u[((size_t)(tt + 1) * BB + bo) * GG + q * HID + nb * 8 + j];
    }
    __syncthreads();

    if (tid < 512) {
      float gate[4];
#pragma unroll
      for (int q = 0; q < 4; q++) {
        int row = q * 8 + j, rt = row >> 4, col = row & 15;
        int wsl = (((within >> 2) + col) & 3) * 4 + (within & 3);  // de-swizzle
        float rec = red[((btE * 2 + 0) * 2 + rt) * 256 + col * 16 + wsl] +
                    red[((btE * 2 + 1) * 2 + rt) * 256 + col * 16 + wsl];
        gate[q] = uv[q] + rec + bh_[q];
      }
      float ig = 1.0f / (1.0f + expf(-gate[0]));
      float fg = 1.0f / (1.0f + expf(-gate[1]));
      float gg = tanhf(gate[2]);
      float og = 1.0f / (1.0f + expf(-gate[3]));
      creg = creg * fg + ig * gg;
      float hh = og * tanhf(creg);

      lout[((size_t)bo * SEQL + gt) * HID + nb * 8 + j] = hh;
      hpk[bo * 8 + j] = __builtin_bit_cast(u16, (_Float16)hh);
      if (gt == SEQL - 1) hout[(size_t)bo * HID + nb * 8 + j] = hh;
      if (tt == T - 1)    cout[(size_t)bo * HID + nb * 8 + j] = creg;
#pragma unroll
      for (int q = 0; q < 4; q++) uv[q] = uvN[q];
    }
    __syncthreads();  // h pack complete

    // ---- coherent h stores: 128 x u64 from packed LDS (proven path) ----
    if (tid < 128) {
      u64 val = *(const u64*)(hpk + sb * 8 + ss * 4);
      coh_store64((gt & 1) ? stA : stB, val);
    }

    if (tt + 1 < T) {
      asm volatile("s_waitcnt vmcnt(0)" ::: "memory");  // drain own stores
      __syncthreads();
      u32 target = (u32)(t0 + tt + 1);
      if (tid == 0) coh_store32(flags + nb * 32, target);
      if (wave == 0) {
        const u32* f0 = flags + (2 * lane) * 32;
        const u32* f1 = flags + (2 * lane + 1) * 32;
        while (!__all(coh_load32(f0) >= target && coh_load32(f1) >= target))
          __builtin_amdgcn_s_sleep(1);
      }
      __syncthreads();
    }
  }
}

extern "C" void kernel_launch(void* const* d_in, const int* in_sizes, int n_in,
                              void* d_out, int out_size, void* d_ws, size_t ws_size,
                              hipStream_t stream) {
  const float* x   = (const float*)d_in[0];
  const float* wih = (const float*)d_in[1];
  const float* whh = (const float*)d_in[2];
  const float* bih = (const float*)d_in[3];
  const float* bhh = (const float*)d_in[4];
  const float* h0  = (const float*)d_in[5];
  const float* c0  = (const float*)d_in[6];
  const float* v0  = (const float*)d_in[7];
  const float* m0  = (const float*)d_in[8];

  float* out  = (float*)d_out;
  float* lout = out;
  float* hout = out + (size_t)BB * SEQL * HID;
  float* cout = hout + (size_t)BB * HID;   // running c
  float* vout = cout + (size_t)BB * HID;   // running v
  float* mout = vout + (size_t)BB * GG;    // running m

  char* ws = (char*)d_ws;
  size_t o = 0;
  _Float16* wih_hi = (_Float16*)(ws + o); o += (size_t)GG * INF * 2;
  _Float16* wih_lo = (_Float16*)(ws + o); o += (size_t)GG * INF * 2;
  _Float16* whh_hi = (_Float16*)(ws + o); o += (size_t)GG * HID * 2;
  _Float16* whh_lo = (_Float16*)(ws + o); o += (size_t)GG * HID * 2;
  _Float16* hA     = (_Float16*)(ws + o); o += (size_t)BB * HID * 2;
  _Float16* hB     = (_Float16*)(ws + o); o += (size_t)BB * HID * 2;
  o = (o + 255) & ~(size_t)255;
  u32* flags = (u32*)(ws + o); o += (size_t)NWG * 32 * 4;
  float* U = (float*)(ws + o);

  const size_t STEP_BYTES = (size_t)BB * GG * sizeof(float);
  size_t cap = (ws_size > o) ? (ws_size - o) / STEP_BYTES : 1;
  if (cap < 1) cap = 1;
  int Tc = (int)(cap < (size_t)SEQL ? cap : (size_t)SEQL);

  transpose_split<<<dim3(GG / 32, INF / 32), 256, 0, stream>>>(wih, wih_hi, wih_lo, INF, GG);
  transpose_split<<<dim3(GG / 32, HID / 32), 256, 0, stream>>>(whh, whh_hi, whh_lo, HID, GG);
  init_state<<<(BB * GG) / 256, 256, 0, stream>>>(h0, c0, v0, m0, cout, vout, mout, hA);
  hipMemsetAsync(flags, 0, (size_t)NWG * 32 * 4, stream);

  for (int t0 = 0; t0 < SEQL; t0 += Tc) {
    int T = (SEQL - t0 < Tc) ? (SEQL - t0) : Tc;
    grad_gemm<<<dim3(T, GG / 128), 256, 0, stream>>>(x, wih_hi, wih_lo, bih, U, t0);
    scan_vm<<<(BB * GG) / 256, 256, 0, stream>>>(U, vout, mout, T);
    rnn_persist<<<NWG, NTHR, SMEM_BYTES, stream>>>(
        U, whh_hi, whh_lo, bhh,
        hA, hB,
        lout, hout, cout, flags, t0, T);
  }
}

// Round 11
// 6501.128 us; speedup vs baseline: 5.9359x; 1.0133x over previous
//
#include <hip/hip_runtime.h>
#include <cstdint>
#include <cstddef>

#define BB   64
#define SEQL 512
#define INF  512
#define HID  1024
#define GG   4096   // 4*HID

#define MU_    0.9f
#define SSTEP_ 0.1f
#define BETA_  0.999f
#define EPS_   1e-16f
#define SCL    2048.0f
#define ISCL   (1.0f / 2048.0f)

#define NWG   64
#define NTHR  1024
#define WLDS  131072                     // W_hh f16 single-plane, frag order
#define RLDS  32768                      // reduce slots (hpk aliases its head)
#define SMEM_BYTES (WLDS + RLDS)         // 163840 = 160 KiB exactly

typedef unsigned short u16;
typedef unsigned int   u32;
typedef unsigned long long u64;
typedef _Float16 half8 __attribute__((ext_vector_type(8)));
typedef float f32x4 __attribute__((ext_vector_type(4)));
typedef u32 u32x4 __attribute__((ext_vector_type(4)));

__device__ __forceinline__ f32x4 mfma16(half8 a, half8 b, f32x4 c) {
  return __builtin_amdgcn_mfma_f32_16x16x32_f16(a, b, c, 0, 0, 0);
}
__device__ __forceinline__ void fsplit(float v, _Float16& hi, _Float16& lo) {
  hi = (_Float16)v;
  lo = (_Float16)((v - (float)hi) * SCL);
}
// device-coherent (cross-XCD) atomic ops for control & h stores (proven path)
__device__ __forceinline__ u32 coh_load32(const u32* p) {
  return __hip_atomic_load(p, __ATOMIC_RELAXED, __HIP_MEMORY_SCOPE_AGENT);
}
__device__ __forceinline__ void coh_store32(u32* p, u32 v) {
  __hip_atomic_store(p, v, __ATOMIC_RELAXED, __HIP_MEMORY_SCOPE_AGENT);
}
__device__ __forceinline__ void coh_store64(u64* p, u64 v) {
  __hip_atomic_store(p, v, __ATOMIC_RELAXED, __HIP_MEMORY_SCOPE_AGENT);
}

// 8 batched device-coherent 16B loads from base addr (+ kk*64B), one asm block.
#define GLD8(o0,o1,o2,o3,o4,o5,o6,o7,addr)                      \
  asm volatile(                                                 \
    "global_load_dwordx4 %0, %8, off sc0 sc1\n\t"               \
    "global_load_dwordx4 %1, %8, off offset:64 sc0 sc1\n\t"     \
    "global_load_dwordx4 %2, %8, off offset:128 sc0 sc1\n\t"    \
    "global_load_dwordx4 %3, %8, off offset:192 sc0 sc1\n\t"    \
    "global_load_dwordx4 %4, %8, off offset:256 sc0 sc1\n\t"    \
    "global_load_dwordx4 %5, %8, off offset:320 sc0 sc1\n\t"    \
    "global_load_dwordx4 %6, %8, off offset:384 sc0 sc1\n\t"    \
    "global_load_dwordx4 %7, %8, off offset:448 sc0 sc1"        \
    : "=&v"(o0), "=&v"(o1), "=&v"(o2), "=&v"(o3),               \
      "=&v"(o4), "=&v"(o5), "=&v"(o6), "=&v"(o7)                \
    : "v"(addr))

// MFMA cluster for one kk: h fragment x 4 rt weight tiles (gates 0..3).
#define HIMF(Hk, kk)                                                        \
  {                                                                         \
    half8 ah = __builtin_bit_cast(half8, Hk);                               \
    const _Float16* wb = Wf + (size_t)((kq * 8 + (kk)) * 4) * 512 + lane * 8;\
    a0 = mfma16(ah, *(const half8*)(wb), a0);                               \
    a1 = mfma16(ah, *(const half8*)(wb + 512), a1);                         \
    a2 = mfma16(ah, *(const half8*)(wb + 1024), a2);                        \
    a3 = mfma16(ah, *(const half8*)(wb + 1536), a3);                        \
  }

// ---- transpose + f16-split: src [R][C] f32 -> dhi/dlo [C][R] f16 ----
__global__ __launch_bounds__(256) void transpose_split(const float* __restrict__ src,
                                                       _Float16* __restrict__ dhi,
                                                       _Float16* __restrict__ dlo,
                                                       int R, int C) {
  __shared__ float tile[32][33];
  int c0 = blockIdx.x * 32, r0 = blockIdx.y * 32;
  int tx = threadIdx.x & 31, ty = threadIdx.x >> 5;
#pragma unroll
  for (int i = 0; i < 32; i += 8)
    tile[ty + i][tx] = src[(size_t)(r0 + ty + i) * C + (c0 + tx)];
  __syncthreads();
#pragma unroll
  for (int i = 0; i < 32; i += 8) {
    float v = tile[tx][ty + i];
    _Float16 hi, lo;
    fsplit(v, hi, lo);
    size_t o = (size_t)(c0 + ty + i) * R + (r0 + tx);
    dhi[o] = hi;
    dlo[o] = lo;
  }
}

// ---- init running state (h -> single f16 plane) ----
__global__ __launch_bounds__(256) void init_state(const float* __restrict__ h0,
                                                  const float* __restrict__ c0,
                                                  const float* __restrict__ v0,
                                                  const float* __restrict__ m0,
                                                  float* __restrict__ co,
                                                  float* __restrict__ vo,
                                                  float* __restrict__ mo,
                                                  _Float16* __restrict__ hhi) {
  int i = blockIdx.x * 256 + threadIdx.x;
  if (i < BB * GG) { vo[i] = v0[i]; mo[i] = m0[i]; }
  if (i < BB * HID) {
    co[i] = c0[i];
    hhi[i] = (_Float16)h0[i];
  }
}

// ---- grad chunk GEMM (f16-split — full precision, sign-critical), 128-col tiles
__global__ __launch_bounds__(256) void grad_gemm(const float* __restrict__ x,
                                                 const _Float16* __restrict__ whi,
                                                 const _Float16* __restrict__ wlo,
                                                 const float* __restrict__ bih,
                                                 float* __restrict__ grad,  // [Tc][B][G]
                                                 int t0) {
  int tloc = blockIdx.x;
  int n0 = blockIdx.y * 128;
  int wave = threadIdx.x >> 6, lane = threadIdx.x & 63;
  int l15 = lane & 15, lg = lane >> 4;
  int t = t0 + tloc;
  int b = 16 * wave + l15;
  const float* xa = x + (size_t)b * (SEQL * INF) + (size_t)t * INF + lg * 8;
  const _Float16* wh = whi + (size_t)(n0 + l15) * INF + lg * 8;
  const _Float16* wl = wlo + (size_t)(n0 + l15) * INF + lg * 8;

  f32x4 accM[8] = {};
  f32x4 accL[8] = {};
  for (int kk = 0; kk < INF; kk += 32) {
    f32x4 x0 = *(const f32x4*)(xa + kk);
    f32x4 x1 = *(const f32x4*)(xa + kk + 4);
    half8 ah, al;
#pragma unroll
    for (int j = 0; j < 4; j++) {
      _Float16 hi, lo;
      fsplit(x0[j], hi, lo); ah[j] = hi; al[j] = lo;
      fsplit(x1[j], hi, lo); ah[4 + j] = hi; al[4 + j] = lo;
    }
#pragma unroll
    for (int nt = 0; nt < 8; nt++) {
      half8 bh = *(const half8*)(wh + (size_t)nt * 16 * INF + kk);
      half8 bl = *(const half8*)(wl + (size_t)nt * 16 * INF + kk);
      accM[nt] = mfma16(ah, bh, accM[nt]);
      accL[nt] = mfma16(al, bh, accL[nt]);
      accL[nt] = mfma16(ah, bl, accL[nt]);
    }
  }
#pragma unroll
  for (int nt = 0; nt < 8; nt++) {
    int g = n0 + nt * 16 + l15;
    float bias = bih[g];
#pragma unroll
    for (int r = 0; r < 4; r++) {
      int bo = 16 * wave + lg * 4 + r;
      grad[((size_t)tloc * BB + bo) * GG + g] = accM[nt][r] + accL[nt][r] * ISCL + bias;
    }
  }
}

// ---- momentum/second-moment scan: grad -> u = v'/(sqrt(m')+eps), in place ----
__global__ __launch_bounds__(256) void scan_vm(float* __restrict__ grad,
                                               float* __restrict__ vst,
                                               float* __restrict__ mst,
                                               int T) {
  int i = blockIdx.x * 256 + threadIdx.x;
  float v = vst[i], m = mst[i];
  for (int tt = 0; tt < T; ++tt) {
    size_t o = (size_t)tt * (BB * GG) + i;
    float g = grad[o];
    v = MU_ * v + SSTEP_ * g;
    m = BETA_ * m + (1.0f - BETA_) * g * g;
    grad[o] = v / (sqrtf(m) + EPS_);
  }
  vst[i] = v;
  mst[i] = m;
}

// ---- persistent recurrent kernel ----
// 64 wgs x 1024 thr (16 waves). wg nb owns cells nb*16..+15 (64 G-rows:
// rt tile = gate q, rows within = cells). W_hh f16 SINGLE plane in LDS
// (frag order, 128 KiB). h broadcast halved: 64 wgs x 128 KiB = 8 MiB/step.
// wave w: bt=w>>2 (16 batch rows), kq=w&3 (K quarter). Barrier: 64 padded
// flags + read-only poll (1 flag/lane). waves_per_eu(4,4) pins VGPR budget.
__global__ __attribute__((amdgpu_flat_work_group_size(NTHR, NTHR),
                          amdgpu_waves_per_eu(4, 4))) void rnn_persist(
    const float* __restrict__ u,          // [T][B][G]
    const _Float16* __restrict__ whh_hi,  // [G][H] f16
    const float* __restrict__ bhh,
    _Float16* __restrict__ hA, _Float16* __restrict__ hB,
    float* __restrict__ lout, float* __restrict__ hout,
    float* __restrict__ cout, u32* __restrict__ flags, int t0, int T) {
  extern __shared__ char smem[];
  _Float16* Wf = (_Float16*)smem;                 // 128 KiB frag-order weights
  float* red = (float*)(smem + WLDS);             // [bt4][kqh2][rt4][col16][16]
  u16* hpk = (u16*)(smem + WLDS);                 // aliases red head (sync-guarded)

  int tid = threadIdx.x;
  int wave = tid >> 6, lane = tid & 63;
  int l15 = lane & 15, lg = lane >> 4;
  int bt = wave >> 2, kq = wave & 3;
  int nb = blockIdx.x;

  // ---- stage W_hh slice into LDS in fragment order ----
  // slot s: ln=s&63; rest=s>>6; rt=rest&3; kk=(rest>>2)&7; kq2=rest>>5
  for (int s = tid; s < 8192; s += NTHR) {
    int ln = s & 63, rest = s >> 6;
    int rt = rest & 3, kk = (rest >> 2) & 7, kq2 = rest >> 5;
    int grow = rt * HID + nb * 16 + (ln & 15);
    int k = kq2 * 256 + kk * 32 + (ln >> 4) * 8;
    *(half8*)(Wf + (size_t)s * 8) = *(const half8*)(whh_hi + (size_t)grow * HID + k);
  }

  // epilogue constants: thread = (batch bo, cell j), all 1024 threads
  int bo = tid >> 4, j = tid & 15;
  int en = nb * 16 + j;
  int within = bo & 15, btE = bo >> 4;
  int wsl = (((within >> 2) + j) & 3) * 4 + (within & 3);  // de-swizzle slot
  float bh_[4], creg, uv[4];
#pragma unroll
  for (int q = 0; q < 4; q++) bh_[q] = bhh[q * HID + en];
  creg = cout[(size_t)bo * HID + en];
#pragma unroll
  for (int q = 0; q < 4; q++)
    uv[q] = u[(size_t)bo * GG + q * HID + en];  // tt=0 prefetch
  // h fragment byte offset for this lane's GEMM A-row
  u64 hOffB = (u64)(((bt * 16 + l15) * HID + kq * 256 + lg * 8) * 2);
  u64 hAB = (u64)(uintptr_t)hA + hOffB;
  u64 hBB = (u64)(uintptr_t)hB + hOffB;
  // h store mapping (tid<256): batch row sb, u64 segment ss of 16 cells
  int sb = tid >> 2, ss = tid & 3;
  u64* stA = (u64*)(hA + (size_t)sb * HID + nb * 16) + ss;
  u64* stB = (u64*)(hB + (size_t)sb * HID + nb * 16) + ss;
  __syncthreads();

  for (int tt = 0; tt < T; ++tt) {
    int gt = t0 + tt;
    u64 rB = (gt & 1) ? hBB : hAB;

    // ---- batched coherent h loads: 8 dwordx4, one asm block ----
    u32x4 H0, H1, H2, H3, H4, H5, H6, H7;
    GLD8(H0, H1, H2, H3, H4, H5, H6, H7, rB);
    asm volatile("s_waitcnt vmcnt(0)" ::: "memory");   // h landed
    __builtin_amdgcn_sched_barrier(0);

    f32x4 a0 = {}, a1 = {}, a2 = {}, a3 = {};
    HIMF(H0, 0) HIMF(H1, 1) HIMF(H2, 2) HIMF(H3, 3)
    HIMF(H4, 4) HIMF(H5, 5) HIMF(H6, 6) HIMF(H7, 7)

    // ---- pairwise kq reduce in LDS, granule-rotation swizzled ----
    int kqh = kq >> 1;
    int p = (lg + l15) & 3;  // rotated granule slot
    int sB0 = (((bt * 2 + kqh) * 4 + 0) * 16 + l15) * 16 + p * 4;
    int sB1 = (((bt * 2 + kqh) * 4 + 1) * 16 + l15) * 16 + p * 4;
    int sB2 = (((bt * 2 + kqh) * 4 + 2) * 16 + l15) * 16 + p * 4;
    int sB3 = (((bt * 2 + kqh) * 4 + 3) * 16 + l15) * 16 + p * 4;
    if (kq & 1) {
      *(f32x4*)(red + sB0) = a0;
      *(f32x4*)(red + sB1) = a1;
      *(f32x4*)(red + sB2) = a2;
      *(f32x4*)(red + sB3) = a3;
    }
    __syncthreads();
    if (!(kq & 1)) {
      *(f32x4*)(red + sB0) = a0 + *(const f32x4*)(red + sB0);
      *(f32x4*)(red + sB1) = a1 + *(const f32x4*)(red + sB1);
      *(f32x4*)(red + sB2) = a2 + *(const f32x4*)(red + sB2);
      *(f32x4*)(red + sB3) = a3 + *(const f32x4*)(red + sB3);
    }
    // prefetch next step's u (overlaps)
    float uvN[4] = {};
    if (tt + 1 < T) {
#pragma unroll
      for (int q = 0; q < 4; q++)
        uvN[q] = u[((size_t)(tt + 1) * BB + bo) * GG + q * HID + en];
    }
    __syncthreads();

    // ---- epilogue: all 1024 threads; red reads -> sync -> hpk write (alias)
    float gate[4];
#pragma unroll
    for (int q = 0; q < 4; q++) {
      float rec = red[(((btE * 2 + 0) * 4 + q) * 16 + j) * 16 + wsl] +
                  red[(((btE * 2 + 1) * 4 + q) * 16 + j) * 16 + wsl];
      gate[q] = uv[q] + rec + bh_[q];
    }
    float ig = 1.0f / (1.0f + expf(-gate[0]));
    float fg = 1.0f / (1.0f + expf(-gate[1]));
    float gg = tanhf(gate[2]);
    float og = 1.0f / (1.0f + expf(-gate[3]));
    creg = creg * fg + ig * gg;
    float hh = og * tanhf(creg);
    __syncthreads();  // all red reads done before hpk (aliased) is written

    lout[((size_t)bo * SEQL + gt) * HID + en] = hh;
    hpk[bo * 16 + j] = __builtin_bit_cast(u16, (_Float16)hh);
    if (gt == SEQL - 1) hout[(size_t)bo * HID + en] = hh;
    if (tt == T - 1)    cout[(size_t)bo * HID + en] = creg;
#pragma unroll
    for (int q = 0; q < 4; q++) uv[q] = uvN[q];
    __syncthreads();  // h pack complete

    // ---- coherent h stores: 256 x u64 from packed LDS (proven path) ----
    if (tid < 256) {
      u64 val = *(const u64*)(hpk + sb * 16 + ss * 4);
      coh_store64((gt & 1) ? stA : stB, val);
    }

    if (tt + 1 < T) {
      asm volatile("s_waitcnt vmcnt(0)" ::: "memory");  // drain own stores
      __syncthreads();
      u32 target = (u32)(t0 + tt + 1);
      if (tid == 0) coh_store32(flags + nb * 32, target);
      if (wave == 0) {
        const u32* f0 = flags + lane * 32;
        while (!__all(coh_load32(f0) >= target))
          __builtin_amdgcn_s_sleep(1);
      }
      __syncthreads();
    }
  }
}

extern "C" void kernel_launch(void* const* d_in, const int* in_sizes, int n_in,
                              void* d_out, int out_size, void* d_ws, size_t ws_size,
                              hipStream_t stream) {
  const float* x   = (const float*)d_in[0];
  const float* wih = (const float*)d_in[1];
  const float* whh = (const float*)d_in[2];
  const float* bih = (const float*)d_in[3];
  const float* bhh = (const float*)d_in[4];
  const float* h0  = (const float*)d_in[5];
  const float* c0  = (const float*)d_in[6];
  const float* v0  = (const float*)d_in[7];
  const float* m0  = (const float*)d_in[8];

  float* out  = (float*)d_out;
  float* lout = out;
  float* hout = out + (size_t)BB * SEQL * HID;
  float* cout = hout + (size_t)BB * HID;   // running c
  float* vout = cout + (size_t)BB * HID;   // running v
  float* mout = vout + (size_t)BB * GG;    // running m

  char* ws = (char*)d_ws;
  size_t o = 0;
  _Float16* wih_hi = (_Float16*)(ws + o); o += (size_t)GG * INF * 2;
  _Float16* wih_lo = (_Float16*)(ws + o); o += (size_t)GG * INF * 2;
  _Float16* whh_hi = (_Float16*)(ws + o); o += (size_t)GG * HID * 2;
  _Float16* whh_lo = (_Float16*)(ws + o); o += (size_t)GG * HID * 2;  // unused by persist
  _Float16* hA     = (_Float16*)(ws + o); o += (size_t)BB * HID * 2;
  _Float16* hB     = (_Float16*)(ws + o); o += (size_t)BB * HID * 2;
  o = (o + 255) & ~(size_t)255;
  u32* flags = (u32*)(ws + o); o += (size_t)NWG * 32 * 4;
  float* U = (float*)(ws + o);

  const size_t STEP_BYTES = (size_t)BB * GG * sizeof(float);
  size_t cap = (ws_size > o) ? (ws_size - o) / STEP_BYTES : 1;
  if (cap < 1) cap = 1;
  int Tc = (int)(cap < (size_t)SEQL ? cap : (size_t)SEQL);

  transpose_split<<<dim3(GG / 32, INF / 32), 256, 0, stream>>>(wih, wih_hi, wih_lo, INF, GG);
  transpose_split<<<dim3(GG / 32, HID / 32), 256, 0, stream>>>(whh, whh_hi, whh_lo, HID, GG);
  init_state<<<(BB * GG) / 256, 256, 0, stream>>>(h0, c0, v0, m0, cout, vout, mout, hA);
  hipMemsetAsync(flags, 0, (size_t)NWG * 32 * 4, stream);

  for (int t0 = 0; t0 < SEQL; t0 += Tc) {
    int T = (SEQL - t0 < Tc) ? (SEQL - t0) : Tc;
    grad_gemm<<<dim3(T, GG / 128), 256, 0, stream>>>(x, wih_hi, wih_lo, bih, U, t0);
    scan_vm<<<(BB * GG) / 256, 256, 0, stream>>>(U, vout, mout, T);
    rnn_persist<<<NWG, NTHR, SMEM_BYTES, stream>>>(
        U, whh_hi, bhh,
        hA, hB,
        lout, hout, cout, flags, t0, T);
  }
}

// Round 12
// 6455.707 us; speedup vs baseline: 5.9776x; 1.0070x over previous
//
#include <hip/hip_runtime.h>
#include <cstdint>
#include <cstddef>

#define BB   64
#define SEQL 512
#define INF  512
#define HID  1024
#define GG   4096   // 4*HID

#define MU_    0.9f
#define SSTEP_ 0.1f
#define BETA_  0.999f
#define EPS_   1e-16f
#define SCL    2048.0f
#define ISCL   (1.0f / 2048.0f)

#define NWG   64
#define NTHR  1024
#define WLDS  131072                     // W_hh f16 single-plane, frag order
#define RLDS  32768                      // reduce slots (hpk aliases its head)
#define SMEM_BYTES (WLDS + RLDS)         // 163840 = 160 KiB exactly

typedef unsigned short u16;
typedef unsigned int   u32;
typedef unsigned long long u64;
typedef _Float16 half8 __attribute__((ext_vector_type(8)));
typedef float f32x4 __attribute__((ext_vector_type(4)));
typedef u32 u32x4 __attribute__((ext_vector_type(4)));

__device__ __forceinline__ f32x4 mfma16(half8 a, half8 b, f32x4 c) {
  return __builtin_amdgcn_mfma_f32_16x16x32_f16(a, b, c, 0, 0, 0);
}
__device__ __forceinline__ void fsplit(float v, _Float16& hi, _Float16& lo) {
  hi = (_Float16)v;
  lo = (_Float16)((v - (float)hi) * SCL);
}
// device-coherent (cross-XCD) atomic ops for control & h stores (proven path)
__device__ __forceinline__ u32 coh_load32(const u32* p) {
  return __hip_atomic_load(p, __ATOMIC_RELAXED, __HIP_MEMORY_SCOPE_AGENT);
}
__device__ __forceinline__ void coh_store32(u32* p, u32 v) {
  __hip_atomic_store(p, v, __ATOMIC_RELAXED, __HIP_MEMORY_SCOPE_AGENT);
}
__device__ __forceinline__ void coh_store64(u64* p, u64 v) {
  __hip_atomic_store(p, v, __ATOMIC_RELAXED, __HIP_MEMORY_SCOPE_AGENT);
}

// 8 batched device-coherent 16B loads from base addr (+ kk*64B), one asm block.
#define GLD8(o0,o1,o2,o3,o4,o5,o6,o7,addr)                      \
  asm volatile(                                                 \
    "global_load_dwordx4 %0, %8, off sc0 sc1\n\t"               \
    "global_load_dwordx4 %1, %8, off offset:64 sc0 sc1\n\t"     \
    "global_load_dwordx4 %2, %8, off offset:128 sc0 sc1\n\t"    \
    "global_load_dwordx4 %3, %8, off offset:192 sc0 sc1\n\t"    \
    "global_load_dwordx4 %4, %8, off offset:256 sc0 sc1\n\t"    \
    "global_load_dwordx4 %5, %8, off offset:320 sc0 sc1\n\t"    \
    "global_load_dwordx4 %6, %8, off offset:384 sc0 sc1\n\t"    \
    "global_load_dwordx4 %7, %8, off offset:448 sc0 sc1"        \
    : "=&v"(o0), "=&v"(o1), "=&v"(o2), "=&v"(o3),               \
      "=&v"(o4), "=&v"(o5), "=&v"(o6), "=&v"(o7)                \
    : "v"(addr))

// MFMA cluster for one kk: h fragment x 4 rt weight tiles (gates 0..3).
#define HIMF(Hk, kk)                                                        \
  {                                                                         \
    half8 ah = __builtin_bit_cast(half8, Hk);                               \
    const _Float16* wb = Wf + (size_t)((kq * 8 + (kk)) * 4) * 512 + lane * 8;\
    a0 = mfma16(ah, *(const half8*)(wb), a0);                               \
    a1 = mfma16(ah, *(const half8*)(wb + 512), a1);                         \
    a2 = mfma16(ah, *(const half8*)(wb + 1024), a2);                        \
    a3 = mfma16(ah, *(const half8*)(wb + 1536), a3);                        \
  }

// ---- transpose + f16-split: src [R][C] f32 -> dhi/dlo [C][R] f16 ----
__global__ __launch_bounds__(256) void transpose_split(const float* __restrict__ src,
                                                       _Float16* __restrict__ dhi,
                                                       _Float16* __restrict__ dlo,
                                                       int R, int C) {
  __shared__ float tile[32][33];
  int c0 = blockIdx.x * 32, r0 = blockIdx.y * 32;
  int tx = threadIdx.x & 31, ty = threadIdx.x >> 5;
#pragma unroll
  for (int i = 0; i < 32; i += 8)
    tile[ty + i][tx] = src[(size_t)(r0 + ty + i) * C + (c0 + tx)];
  __syncthreads();
#pragma unroll
  for (int i = 0; i < 32; i += 8) {
    float v = tile[tx][ty + i];
    _Float16 hi, lo;
    fsplit(v, hi, lo);
    size_t o = (size_t)(c0 + ty + i) * R + (r0 + tx);
    dhi[o] = hi;
    dlo[o] = lo;
  }
}

// ---- pre-split x: f32 [B*S][IN] -> f16 [B*S][2][IN] (hi plane, lo plane) ----
// Removes the 32x-redundant in-kernel fsplit from grad_gemm (VALU bound).
__global__ __launch_bounds__(256) void split_x(const float* __restrict__ x,
                                               _Float16* __restrict__ xs) {
  size_t i = (size_t)blockIdx.x * 256 + threadIdx.x;   // one 8-elem chunk
  size_t e = i * 8;
  size_t r = e / INF, col = e % INF;
  f32x4 v0 = *(const f32x4*)(x + e);
  f32x4 v1 = *(const f32x4*)(x + e + 4);
  half8 hi, lo;
#pragma unroll
  for (int j = 0; j < 4; j++) {
    _Float16 h_, l_;
    fsplit(v0[j], h_, l_); hi[j] = h_; lo[j] = l_;
    fsplit(v1[j], h_, l_); hi[4 + j] = h_; lo[4 + j] = l_;
  }
  _Float16* dst = xs + r * 2 * INF + col;
  *(half8*)(dst) = hi;
  *(half8*)(dst + INF) = lo;
}

// ---- init running state (h -> single f16 plane) ----
__global__ __launch_bounds__(256) void init_state(const float* __restrict__ h0,
                                                  const float* __restrict__ c0,
                                                  const float* __restrict__ v0,
                                                  const float* __restrict__ m0,
                                                  float* __restrict__ co,
                                                  float* __restrict__ vo,
                                                  float* __restrict__ mo,
                                                  _Float16* __restrict__ hhi) {
  int i = blockIdx.x * 256 + threadIdx.x;
  if (i < BB * GG) { vo[i] = v0[i]; mo[i] = m0[i]; }
  if (i < BB * HID) {
    co[i] = c0[i];
    hhi[i] = (_Float16)h0[i];
  }
}

// ---- grad chunk GEMM (f16-split — full precision, sign-critical), 128-col tiles
// consumes PRE-SPLIT x planes (no in-loop VALU split; bit-identical math)
__global__ __launch_bounds__(256) void grad_gemm(const _Float16* __restrict__ xs, // [B*S][2][IN]
                                                 const _Float16* __restrict__ whi,
                                                 const _Float16* __restrict__ wlo,
                                                 const float* __restrict__ bih,
                                                 float* __restrict__ grad,  // [Tc][B][G]
                                                 int t0) {
  int tloc = blockIdx.x;
  int n0 = blockIdx.y * 128;
  int wave = threadIdx.x >> 6, lane = threadIdx.x & 63;
  int l15 = lane & 15, lg = lane >> 4;
  int t = t0 + tloc;
  int b = 16 * wave + l15;
  const _Float16* xh = xs + ((size_t)b * SEQL + t) * 2 * INF + lg * 8;
  const _Float16* wh = whi + (size_t)(n0 + l15) * INF + lg * 8;
  const _Float16* wl = wlo + (size_t)(n0 + l15) * INF + lg * 8;

  f32x4 accM[8] = {};
  f32x4 accL[8] = {};
  for (int kk = 0; kk < INF; kk += 32) {
    half8 ah = *(const half8*)(xh + kk);
    half8 al = *(const half8*)(xh + INF + kk);
#pragma unroll
    for (int nt = 0; nt < 8; nt++) {
      half8 bh = *(const half8*)(wh + (size_t)nt * 16 * INF + kk);
      half8 bl = *(const half8*)(wl + (size_t)nt * 16 * INF + kk);
      accM[nt] = mfma16(ah, bh, accM[nt]);
      accL[nt] = mfma16(al, bh, accL[nt]);
      accL[nt] = mfma16(ah, bl, accL[nt]);
    }
  }
#pragma unroll
  for (int nt = 0; nt < 8; nt++) {
    int g = n0 + nt * 16 + l15;
    float bias = bih[g];
#pragma unroll
    for (int r = 0; r < 4; r++) {
      int bo = 16 * wave + lg * 4 + r;
      grad[((size_t)tloc * BB + bo) * GG + g] = accM[nt][r] + accL[nt][r] * ISCL + bias;
    }
  }
}

// ---- momentum/second-moment scan: grad -> u = v'/(sqrt(m')+eps), in place ----
__global__ __launch_bounds__(256) void scan_vm(float* __restrict__ grad,
                                               float* __restrict__ vst,
                                               float* __restrict__ mst,
                                               int T) {
  int i = blockIdx.x * 256 + threadIdx.x;
  float v = vst[i], m = mst[i];
  for (int tt = 0; tt < T; ++tt) {
    size_t o = (size_t)tt * (BB * GG) + i;
    float g = grad[o];
    v = MU_ * v + SSTEP_ * g;
    m = BETA_ * m + (1.0f - BETA_) * g * g;
    grad[o] = v / (sqrtf(m) + EPS_);
  }
  vst[i] = v;
  mst[i] = m;
}

// ---- persistent recurrent kernel (UNCHANGED from round 11 — proven) ----
// 64 wgs x 1024 thr (16 waves). wg nb owns cells nb*16..+15. W_hh f16 single
// plane in LDS (frag order). h broadcast: 64 wgs x 128 KiB = 8 MiB/step.
__global__ __attribute__((amdgpu_flat_work_group_size(NTHR, NTHR),
                          amdgpu_waves_per_eu(4, 4))) void rnn_persist(
    const float* __restrict__ u,          // [T][B][G]
    const _Float16* __restrict__ whh_hi,  // [G][H] f16
    const float* __restrict__ bhh,
    _Float16* __restrict__ hA, _Float16* __restrict__ hB,
    float* __restrict__ lout, float* __restrict__ hout,
    float* __restrict__ cout, u32* __restrict__ flags, int t0, int T) {
  extern __shared__ char smem[];
  _Float16* Wf = (_Float16*)smem;                 // 128 KiB frag-order weights
  float* red = (float*)(smem + WLDS);             // [bt4][kqh2][rt4][col16][16]
  u16* hpk = (u16*)(smem + WLDS);                 // aliases red head (sync-guarded)

  int tid = threadIdx.x;
  int wave = tid >> 6, lane = tid & 63;
  int l15 = lane & 15, lg = lane >> 4;
  int bt = wave >> 2, kq = wave & 3;
  int nb = blockIdx.x;

  // ---- stage W_hh slice into LDS in fragment order ----
  for (int s = tid; s < 8192; s += NTHR) {
    int ln = s & 63, rest = s >> 6;
    int rt = rest & 3, kk = (rest >> 2) & 7, kq2 = rest >> 5;
    int grow = rt * HID + nb * 16 + (ln & 15);
    int k = kq2 * 256 + kk * 32 + (ln >> 4) * 8;
    *(half8*)(Wf + (size_t)s * 8) = *(const half8*)(whh_hi + (size_t)grow * HID + k);
  }

  // epilogue constants: thread = (batch bo, cell j), all 1024 threads
  int bo = tid >> 4, j = tid & 15;
  int en = nb * 16 + j;
  int within = bo & 15, btE = bo >> 4;
  int wsl = (((within >> 2) + j) & 3) * 4 + (within & 3);  // de-swizzle slot
  float bh_[4], creg, uv[4];
#pragma unroll
  for (int q = 0; q < 4; q++) bh_[q] = bhh[q * HID + en];
  creg = cout[(size_t)bo * HID + en];
#pragma unroll
  for (int q = 0; q < 4; q++)
    uv[q] = u[(size_t)bo * GG + q * HID + en];  // tt=0 prefetch
  // h fragment byte offset for this lane's GEMM A-row
  u64 hOffB = (u64)(((bt * 16 + l15) * HID + kq * 256 + lg * 8) * 2);
  u64 hAB = (u64)(uintptr_t)hA + hOffB;
  u64 hBB = (u64)(uintptr_t)hB + hOffB;
  // h store mapping (tid<256): batch row sb, u64 segment ss of 16 cells
  int sb = tid >> 2, ss = tid & 3;
  u64* stA = (u64*)(hA + (size_t)sb * HID + nb * 16) + ss;
  u64* stB = (u64*)(hB + (size_t)sb * HID + nb * 16) + ss;
  __syncthreads();

  for (int tt = 0; tt < T; ++tt) {
    int gt = t0 + tt;
    u64 rB = (gt & 1) ? hBB : hAB;

    // ---- batched coherent h loads: 8 dwordx4, one asm block ----
    u32x4 H0, H1, H2, H3, H4, H5, H6, H7;
    GLD8(H0, H1, H2, H3, H4, H5, H6, H7, rB);
    asm volatile("s_waitcnt vmcnt(0)" ::: "memory");   // h landed
    __builtin_amdgcn_sched_barrier(0);

    f32x4 a0 = {}, a1 = {}, a2 = {}, a3 = {};
    HIMF(H0, 0) HIMF(H1, 1) HIMF(H2, 2) HIMF(H3, 3)
    HIMF(H4, 4) HIMF(H5, 5) HIMF(H6, 6) HIMF(H7, 7)

    // ---- pairwise kq reduce in LDS, granule-rotation swizzled ----
    int kqh = kq >> 1;
    int p = (lg + l15) & 3;  // rotated granule slot
    int sB0 = (((bt * 2 + kqh) * 4 + 0) * 16 + l15) * 16 + p * 4;
    int sB1 = (((bt * 2 + kqh) * 4 + 1) * 16 + l15) * 16 + p * 4;
    int sB2 = (((bt * 2 + kqh) * 4 + 2) * 16 + l15) * 16 + p * 4;
    int sB3 = (((bt * 2 + kqh) * 4 + 3) * 16 + l15) * 16 + p * 4;
    if (kq & 1) {
      *(f32x4*)(red + sB0) = a0;
      *(f32x4*)(red + sB1) = a1;
      *(f32x4*)(red + sB2) = a2;
      *(f32x4*)(red + sB3) = a3;
    }
    __syncthreads();
    if (!(kq & 1)) {
      *(f32x4*)(red + sB0) = a0 + *(const f32x4*)(red + sB0);
      *(f32x4*)(red + sB1) = a1 + *(const f32x4*)(red + sB1);
      *(f32x4*)(red + sB2) = a2 + *(const f32x4*)(red + sB2);
      *(f32x4*)(red + sB3) = a3 + *(const f32x4*)(red + sB3);
    }
    // prefetch next step's u (overlaps)
    float uvN[4] = {};
    if (tt + 1 < T) {
#pragma unroll
      for (int q = 0; q < 4; q++)
        uvN[q] = u[((size_t)(tt + 1) * BB + bo) * GG + q * HID + en];
    }
    __syncthreads();

    // ---- epilogue: all 1024 threads; red reads -> sync -> hpk write (alias)
    float gate[4];
#pragma unroll
    for (int q = 0; q < 4; q++) {
      float rec = red[(((btE * 2 + 0) * 4 + q) * 16 + j) * 16 + wsl] +
                  red[(((btE * 2 + 1) * 4 + q) * 16 + j) * 16 + wsl];
      gate[q] = uv[q] + rec + bh_[q];
    }
    float ig = 1.0f / (1.0f + expf(-gate[0]));
    float fg = 1.0f / (1.0f + expf(-gate[1]));
    float gg = tanhf(gate[2]);
    float og = 1.0f / (1.0f + expf(-gate[3]));
    creg = creg * fg + ig * gg;
    float hh = og * tanhf(creg);
    __syncthreads();  // all red reads done before hpk (aliased) is written

    lout[((size_t)bo * SEQL + gt) * HID + en] = hh;
    hpk[bo * 16 + j] = __builtin_bit_cast(u16, (_Float16)hh);
    if (gt == SEQL - 1) hout[(size_t)bo * HID + en] = hh;
    if (tt == T - 1)    cout[(size_t)bo * HID + en] = creg;
#pragma unroll
    for (int q = 0; q < 4; q++) uv[q] = uvN[q];
    __syncthreads();  // h pack complete

    // ---- coherent h stores: 256 x u64 from packed LDS (proven path) ----
    if (tid < 256) {
      u64 val = *(const u64*)(hpk + sb * 16 + ss * 4);
      coh_store64((gt & 1) ? stA : stB, val);
    }

    if (tt + 1 < T) {
      asm volatile("s_waitcnt vmcnt(0)" ::: "memory");  // drain own stores
      __syncthreads();
      u32 target = (u32)(t0 + tt + 1);
      if (tid == 0) coh_store32(flags + nb * 32, target);
      if (wave == 0) {
        const u32* f0 = flags + lane * 32;
        while (!__all(coh_load32(f0) >= target))
          __builtin_amdgcn_s_sleep(1);
      }
      __syncthreads();
    }
  }
}

extern "C" void kernel_launch(void* const* d_in, const int* in_sizes, int n_in,
                              void* d_out, int out_size, void* d_ws, size_t ws_size,
                              hipStream_t stream) {
  const float* x   = (const float*)d_in[0];
  const float* wih = (const float*)d_in[1];
  const float* whh = (const float*)d_in[2];
  const float* bih = (const float*)d_in[3];
  const float* bhh = (const float*)d_in[4];
  const float* h0  = (const float*)d_in[5];
  const float* c0  = (const float*)d_in[6];
  const float* v0  = (const float*)d_in[7];
  const float* m0  = (const float*)d_in[8];

  float* out  = (float*)d_out;
  float* lout = out;
  float* hout = out + (size_t)BB * SEQL * HID;
  float* cout = hout + (size_t)BB * HID;   // running c
  float* vout = cout + (size_t)BB * HID;   // running v
  float* mout = vout + (size_t)BB * GG;    // running m

  char* ws = (char*)d_ws;
  size_t o = 0;
  _Float16* wih_hi = (_Float16*)(ws + o); o += (size_t)GG * INF * 2;
  _Float16* wih_lo = (_Float16*)(ws + o); o += (size_t)GG * INF * 2;
  _Float16* whh_hi = (_Float16*)(ws + o); o += (size_t)GG * HID * 2;
  _Float16* whh_lo = (_Float16*)(ws + o); o += (size_t)GG * HID * 2;  // unused by persist
  _Float16* xs     = (_Float16*)(ws + o); o += (size_t)BB * SEQL * 2 * INF * 2;  // 64 MiB
  _Float16* hA     = (_Float16*)(ws + o); o += (size_t)BB * HID * 2;
  _Float16* hB     = (_Float16*)(ws + o); o += (size_t)BB * HID * 2;
  o = (o + 255) & ~(size_t)255;
  u32* flags = (u32*)(ws + o); o += (size_t)NWG * 32 * 4;
  float* U = (float*)(ws + o);

  const size_t STEP_BYTES = (size_t)BB * GG * sizeof(float);
  size_t cap = (ws_size > o) ? (ws_size - o) / STEP_BYTES : 1;
  if (cap < 1) cap = 1;
  int Tc = (int)(cap < (size_t)SEQL ? cap : (size_t)SEQL);

  split_x<<<(BB * SEQL * INF / 8) / 256, 256, 0, stream>>>(x, xs);
  transpose_split<<<dim3(GG / 32, INF / 32), 256, 0, stream>>>(wih, wih_hi, wih_lo, INF, GG);
  transpose_split<<<dim3(GG / 32, HID / 32), 256, 0, stream>>>(whh, whh_hi, whh_lo, HID, GG);
  init_state<<<(BB * GG) / 256, 256, 0, stream>>>(h0, c0, v0, m0, cout, vout, mout, hA);
  hipMemsetAsync(flags, 0, (size_t)NWG * 32 * 4, stream);

  for (int t0 = 0; t0 < SEQL; t0 += Tc) {
    int T = (SEQL - t0 < Tc) ? (SEQL - t0) : Tc;
    grad_gemm<<<dim3(T, GG / 128), 256, 0, stream>>>(xs, wih_hi, wih_lo, bih, U, t0);
    scan_vm<<<(BB * GG) / 256, 256, 0, stream>>>(U, vout, mout, T);
    rnn_persist<<<NWG, NTHR, SMEM_BYTES, stream>>>(
        U, whh_hi, bhh,
        hA, hB,
        lout, hout, cout, flags, t0, T);
  }
}